// Round 1
// baseline (18018.089 us; speedup 1.0000x reference)
//
#include <hip/hip_runtime.h>
#include <math.h>

// ---------------- constants ----------------
#define NIMG 32
#define NP2  196        // patches per image
#define PTOK 197        // tokens per image
#define DIM  768
#define NH   12
#define VD   64
#define MLPD 3072
#define ROWS (NIMG*PTOK)   // 6304
#define PROWS (NIMG*NP2)   // 6272

// ---------------- patchify ----------------
__global__ __launch_bounds__(256) void patchify_kernel(const float* __restrict__ img,
                                                       float* __restrict__ out)
{
    int idx = blockIdx.x * 256 + threadIdx.x;
    if (idx >= PROWS * DIM) return;
    int row = idx / DIM, kk = idx % DIM;
    int b = row / NP2, p = row % NP2;
    int i = p / 14, j = p % 14;
    int c = kk >> 8, r = kk & 255;
    int ph = r >> 4, pw = r & 15;
    out[idx] = img[(((size_t)b*3 + c)*224 + i*16 + ph)*224 + j*16 + pw];
}

// ---------------- class token + pos row0 ----------------
__global__ __launch_bounds__(256) void class_pos_kernel(const float* __restrict__ ct,
                                                        const float* __restrict__ pos,
                                                        float* __restrict__ x)
{
    int idx = blockIdx.x * 256 + threadIdx.x;
    if (idx >= NIMG * DIM) return;
    int b = idx / DIM, d = idx % DIM;
    x[(size_t)b * PTOK * DIM + d] = ct[d] + pos[d];
}

// ---------------- generic fp32 GEMM, 64x64 tile, 256 thr, 4x4/thr ----------------
// MODE 1: embed   -> write x[b,1+p,:] = acc + pos[1+p,:]
// MODE 2: qkv     -> scatter to q/k/v [b,h,p,v]
// MODE 3: bias+gelu(exact) -> C
// MODE 4: residual: C = res + acc
// MODE 5: bias+residual: C = res + acc + bias
template<int MODE>
__global__ __launch_bounds__(256) void gemm_kernel(
    const float* __restrict__ A, const float* __restrict__ B,
    float* __restrict__ C, int M, int N, int K,
    const float* __restrict__ bias, const float* __restrict__ res,
    const float* __restrict__ pos,
    float* __restrict__ qo, float* __restrict__ ko, float* __restrict__ vo)
{
    __shared__ __align__(16) float As[16][68];
    __shared__ __align__(16) float Bs[16][68];
    const int tid = threadIdx.x;
    const int tx = tid & 15, ty = tid >> 4;
    const int m0 = blockIdx.y * 64, n0 = blockIdx.x * 64;

    float acc[4][4] = {};

    const int arow  = tid >> 2;        // 0..63
    const int acol4 = (tid & 3) * 4;   // 0,4,8,12
    const int brow  = tid >> 4;        // 0..15
    const int bcol4 = (tid & 15) * 4;  // 0..60

    for (int k0 = 0; k0 < K; k0 += 16) {
        {   // A tile 64x16, transposed store
            int grow = m0 + arow;
            float4 av = make_float4(0.f, 0.f, 0.f, 0.f);
            if (grow < M) av = *(const float4*)&A[(size_t)grow * K + k0 + acol4];
            As[acol4 + 0][arow] = av.x;
            As[acol4 + 1][arow] = av.y;
            As[acol4 + 2][arow] = av.z;
            As[acol4 + 3][arow] = av.w;
        }
        {   // B tile 16x64
            float4 bv = *(const float4*)&B[(size_t)(k0 + brow) * N + n0 + bcol4];
            *(float4*)&Bs[brow][bcol4] = bv;
        }
        __syncthreads();
        #pragma unroll
        for (int kk = 0; kk < 16; ++kk) {
            float4 a = *(const float4*)&As[kk][ty * 4];
            float4 b = *(const float4*)&Bs[kk][tx * 4];
            acc[0][0] += a.x*b.x; acc[0][1] += a.x*b.y; acc[0][2] += a.x*b.z; acc[0][3] += a.x*b.w;
            acc[1][0] += a.y*b.x; acc[1][1] += a.y*b.y; acc[1][2] += a.y*b.z; acc[1][3] += a.y*b.w;
            acc[2][0] += a.z*b.x; acc[2][1] += a.z*b.y; acc[2][2] += a.z*b.z; acc[2][3] += a.z*b.w;
            acc[3][0] += a.w*b.x; acc[3][1] += a.w*b.y; acc[3][2] += a.w*b.z; acc[3][3] += a.w*b.w;
        }
        __syncthreads();
    }

    #pragma unroll
    for (int mi = 0; mi < 4; ++mi) {
        int r = m0 + ty * 4 + mi;
        if (r >= M) continue;
        #pragma unroll
        for (int ni = 0; ni < 4; ++ni) {
            int c = n0 + tx * 4 + ni;
            float val = acc[mi][ni];
            if (MODE == 1) {
                int b = r / NP2, p = r % NP2;
                C[((size_t)b * PTOK + 1 + p) * DIM + c] = val + pos[(size_t)(p + 1) * DIM + c];
            } else if (MODE == 2) {
                int b = r / PTOK, p = r % PTOK;
                int t = c % 3, hv = c / 3;
                size_t dst = (((size_t)b * NH + (hv >> 6)) * PTOK + p) * VD + (hv & 63);
                (t == 0 ? qo : t == 1 ? ko : vo)[dst] = val;
            } else if (MODE == 3) {
                float tmp = val + bias[c];
                C[(size_t)r * N + c] = 0.5f * tmp * (1.0f + erff(tmp * 0.70710678118654752f));
            } else if (MODE == 4) {
                C[(size_t)r * N + c] = res[(size_t)r * N + c] + val;
            } else if (MODE == 5) {
                C[(size_t)r * N + c] = res[(size_t)r * N + c] + val + bias[c];
            } else {
                C[(size_t)r * N + c] = val;
            }
        }
    }
}

// ---------------- LayerNorm: 1 wave per row ----------------
__global__ __launch_bounds__(256) void ln_kernel(const float* __restrict__ x,
                                                 const float* __restrict__ w,
                                                 const float* __restrict__ b,
                                                 float* __restrict__ out, int rows)
{
    int wave = threadIdx.x >> 6, lane = threadIdx.x & 63;
    int row = blockIdx.x * 4 + wave;
    if (row >= rows) return;
    const float* xr = x + (size_t)row * DIM;
    float vals[12];
    float sum = 0.f;
    #pragma unroll
    for (int u = 0; u < 12; ++u) { vals[u] = xr[u * 64 + lane]; sum += vals[u]; }
    #pragma unroll
    for (int off = 32; off; off >>= 1) sum += __shfl_xor(sum, off);
    float mean = sum * (1.f / DIM);
    float vs = 0.f;
    #pragma unroll
    for (int u = 0; u < 12; ++u) { float d = vals[u] - mean; vs += d * d; }
    #pragma unroll
    for (int off = 32; off; off >>= 1) vs += __shfl_xor(vs, off);
    float rstd = rsqrtf(vs * (1.f / DIM) + 1e-5f);
    float* orow = out + (size_t)row * DIM;
    #pragma unroll
    for (int u = 0; u < 12; ++u) {
        int d = u * 64 + lane;
        orow[d] = (vals[u] - mean) * rstd * w[d] + b[d];
    }
}

// ---------------- fused attention: one block per (bh, 32-row i-tile) ----------------
__global__ __launch_bounds__(256) void attn_kernel(const float* __restrict__ qg,
                                                   const float* __restrict__ kg,
                                                   const float* __restrict__ vg,
                                                   float* __restrict__ og)
{
    __shared__ __align__(16) float klds[104][68];
    __shared__ __align__(16) float qlds[32][68];
    __shared__ __align__(16) float slds[32][200];
    __shared__ float rinv[32];

    const int bh = blockIdx.y;
    const int i0 = blockIdx.x * 32;
    const int b = bh / NH, hh = bh - b * NH;
    const float* qb = qg + (size_t)bh * PTOK * VD;
    const float* kb = kg + (size_t)bh * PTOK * VD;
    const float* vb = vg + (size_t)bh * PTOK * VD;
    const int tid = threadIdx.x;

    // stage Q tile
    for (int idx = tid; idx < 32 * 64; idx += 256) {
        int i = idx >> 6, vv = idx & 63;
        int gi = i0 + i;
        qlds[i][vv] = (gi < PTOK) ? qb[(size_t)gi * VD + vv] : 0.f;
    }

    const int i = tid >> 3, jg = tid & 7;
    float s[25];
    #pragma unroll
    for (int jj = 0; jj < 25; ++jj) s[jj] = -INFINITY;

    // K in two chunks to fit 64KB LDS: [0,104), [104,197)
    for (int chunk = 0; chunk < 2; ++chunk) {
        int jbase = chunk * 104;
        int jcount = (chunk == 0) ? 104 : (PTOK - 104);
        __syncthreads();
        for (int idx = tid; idx < jcount * 64; idx += 256) {
            int j = idx >> 6, vv = idx & 63;
            klds[j][vv] = kb[(size_t)(jbase + j) * VD + vv];
        }
        __syncthreads();
        int jjs = (chunk == 0) ? 0 : 13;
        int jje = (chunk == 0) ? 13 : 25;
        for (int jj = jjs; jj < jje; ++jj) {
            int j = jg + jj * 8;
            if (j >= PTOK) break;
            int jl = j - jbase;
            float acc = 0.f;
            #pragma unroll
            for (int vv = 0; vv < 64; vv += 4) {
                float4 qa = *(const float4*)&qlds[i][vv];
                float4 ka = *(const float4*)&klds[jl][vv];
                acc += qa.x*ka.x + qa.y*ka.y + qa.z*ka.z + qa.w*ka.w;
            }
            s[jj] = acc * 0.125f;
        }
    }

    // softmax across the 8 jg lanes of each row
    float m = -INFINITY;
    #pragma unroll
    for (int jj = 0; jj < 25; ++jj) m = fmaxf(m, s[jj]);
    #pragma unroll
    for (int off = 1; off < 8; off <<= 1) m = fmaxf(m, __shfl_xor(m, off));
    float sum = 0.f;
    #pragma unroll
    for (int jj = 0; jj < 25; ++jj) {
        int j = jg + jj * 8;
        float p = (s[jj] == -INFINITY) ? 0.f : expf(s[jj] - m);
        if (j < PTOK) slds[i][j] = p;
        sum += p;
    }
    #pragma unroll
    for (int off = 1; off < 8; off <<= 1) sum += __shfl_xor(sum, off);
    if (jg == 0) rinv[i] = 1.f / sum;
    __syncthreads();

    // PV: thread (ig, vv) accumulates 8 rows
    const int vv = tid & 63, ig = tid >> 6;
    float accv[8] = {};
    for (int j4 = 0; j4 < 196; j4 += 4) {
        float v0 = vb[(size_t)(j4 + 0) * VD + vv];
        float v1 = vb[(size_t)(j4 + 1) * VD + vv];
        float v2 = vb[(size_t)(j4 + 2) * VD + vv];
        float v3 = vb[(size_t)(j4 + 3) * VD + vv];
        #pragma unroll
        for (int u = 0; u < 8; ++u) {
            float4 sv = *(const float4*)&slds[ig * 8 + u][j4];
            accv[u] += sv.x * v0 + sv.y * v1 + sv.z * v2 + sv.w * v3;
        }
    }
    {
        float v0 = vb[(size_t)196 * VD + vv];
        #pragma unroll
        for (int u = 0; u < 8; ++u) accv[u] += slds[ig * 8 + u][196] * v0;
    }
    #pragma unroll
    for (int u = 0; u < 8; ++u) {
        int i2 = ig * 8 + u, gi = i0 + i2;
        if (gi < PTOK)
            og[((size_t)b * PTOK + gi) * DIM + hh * VD + vv] = accv[u] * rinv[i2];
    }
}

// ---------------- head: logits + softmax, one block per image ----------------
__global__ __launch_bounds__(256) void head_kernel(const float* __restrict__ x,
                                                   const float* __restrict__ W,
                                                   const float* __restrict__ bias,
                                                   float* __restrict__ out)
{
    __shared__ __align__(16) float xl[DIM];
    __shared__ float red[4];
    int b = blockIdx.x;
    const float* xr = x + (size_t)b * PTOK * DIM;
    for (int idx = threadIdx.x; idx < DIM; idx += 256) xl[idx] = xr[idx];
    __syncthreads();

    float logit[4];
    #pragma unroll
    for (int u = 0; u < 4; ++u) {
        int c = threadIdx.x + u * 256;
        float acc = (c < 1000) ? bias[c] : -INFINITY;
        if (c < 1000) {
            for (int k = 0; k < DIM; k += 4) {
                float4 xv = *(const float4*)&xl[k];
                acc += xv.x * W[(size_t)k * 1000 + c]
                     + xv.y * W[(size_t)(k + 1) * 1000 + c]
                     + xv.z * W[(size_t)(k + 2) * 1000 + c]
                     + xv.w * W[(size_t)(k + 3) * 1000 + c];
            }
        }
        logit[u] = acc;
    }
    int lane = threadIdx.x & 63, wv = threadIdx.x >> 6;
    float m = fmaxf(fmaxf(logit[0], logit[1]), fmaxf(logit[2], logit[3]));
    #pragma unroll
    for (int off = 32; off; off >>= 1) m = fmaxf(m, __shfl_xor(m, off));
    if (lane == 0) red[wv] = m;
    __syncthreads();
    m = fmaxf(fmaxf(red[0], red[1]), fmaxf(red[2], red[3]));

    float p[4]; float sum = 0.f;
    #pragma unroll
    for (int u = 0; u < 4; ++u) {
        int c = threadIdx.x + u * 256;
        p[u] = (c < 1000) ? expf(logit[u] - m) : 0.f;
        sum += p[u];
    }
    #pragma unroll
    for (int off = 32; off; off >>= 1) sum += __shfl_xor(sum, off);
    __syncthreads();
    if (lane == 0) red[wv] = sum;
    __syncthreads();
    float inv = 1.f / (red[0] + red[1] + red[2] + red[3]);
    #pragma unroll
    for (int u = 0; u < 4; ++u) {
        int c = threadIdx.x + u * 256;
        if (c < 1000) out[(size_t)b * 1000 + c] = p[u] * inv;
    }
}

// ---------------- launcher ----------------
extern "C" void kernel_launch(void* const* d_in, const int* in_sizes, int n_in,
                              void* d_out, int out_size, void* d_ws, size_t ws_size,
                              hipStream_t stream)
{
    const float* images  = (const float*)d_in[0];
    const float* W_map   = (const float*)d_in[1];
    const float* ct      = (const float*)d_in[2];
    const float* pos     = (const float*)d_in[3];
    const float* ln1_w   = (const float*)d_in[4];
    const float* ln1_b   = (const float*)d_in[5];
    const float* qkv_w   = (const float*)d_in[6];
    const float* merge_w = (const float*)d_in[7];
    const float* ln2_w   = (const float*)d_in[8];
    const float* ln2_b   = (const float*)d_in[9];
    const float* mlp_w1  = (const float*)d_in[10];
    const float* mlp_b1  = (const float*)d_in[11];
    const float* mlp_w2  = (const float*)d_in[12];
    const float* mlp_b2  = (const float*)d_in[13];
    const float* head_w  = (const float*)d_in[14];
    const float* head_b  = (const float*)d_in[15];
    float* out = (float*)d_out;

    float* ws = (float*)d_ws;
    const size_t XE = (size_t)ROWS * DIM;   // 4,841,472
    float* x  = ws;
    float* h  = x  + XE;
    float* qb = h  + XE;
    float* kb = qb + XE;
    float* vb = kb + XE;
    float* ob = vb + XE;
    float* g  = ob + XE;                    // ROWS*MLPD
    float* patches = g;                     // alias: used only before g

    patchify_kernel<<<(PROWS * DIM + 255) / 256, 256, 0, stream>>>(images, patches);
    class_pos_kernel<<<(NIMG * DIM + 255) / 256, 256, 0, stream>>>(ct, pos, x);
    gemm_kernel<1><<<dim3(DIM / 64, PROWS / 64), 256, 0, stream>>>(
        patches, W_map, x, PROWS, DIM, DIM, nullptr, nullptr, pos, nullptr, nullptr, nullptr);

    const int mblk = (ROWS + 63) / 64;  // 99
    for (int l = 0; l < 12; ++l) {
        ln_kernel<<<(ROWS + 3) / 4, 256, 0, stream>>>(x, ln1_w + l * DIM, ln1_b + l * DIM, h, ROWS);
        gemm_kernel<2><<<dim3(2304 / 64, mblk), 256, 0, stream>>>(
            h, qkv_w + (size_t)l * DIM * 2304, nullptr, ROWS, 2304, DIM,
            nullptr, nullptr, nullptr, qb, kb, vb);
        attn_kernel<<<dim3(7, NIMG * NH), 256, 0, stream>>>(qb, kb, vb, ob);
        gemm_kernel<4><<<dim3(DIM / 64, mblk), 256, 0, stream>>>(
            ob, merge_w + (size_t)l * DIM * DIM, x, ROWS, DIM, DIM,
            nullptr, x, nullptr, nullptr, nullptr, nullptr);
        ln_kernel<<<(ROWS + 3) / 4, 256, 0, stream>>>(x, ln2_w + l * DIM, ln2_b + l * DIM, h, ROWS);
        gemm_kernel<3><<<dim3(MLPD / 64, mblk), 256, 0, stream>>>(
            h, mlp_w1 + (size_t)l * DIM * MLPD, g, ROWS, MLPD, DIM,
            mlp_b1 + (size_t)l * MLPD, nullptr, nullptr, nullptr, nullptr, nullptr);
        gemm_kernel<5><<<dim3(DIM / 64, mblk), 256, 0, stream>>>(
            g, mlp_w2 + (size_t)l * MLPD * DIM, x, ROWS, DIM, MLPD,
            mlp_b2 + (size_t)l * DIM, x, nullptr, nullptr, nullptr, nullptr);
    }
    head_kernel<<<NIMG, 256, 0, stream>>>(x, head_w, head_b, out);
}

// Round 2
// 8631.056 us; speedup vs baseline: 2.0876x; 2.0876x over previous
//
#include <hip/hip_runtime.h>
#include <math.h>

// ---------------- constants ----------------
#define NIMG 32
#define NP2  196        // patches per image
#define PTOK 197        // tokens per image
#define DIM  768
#define NH   12
#define VD   64
#define MLPD 3072
#define ROWS (NIMG*PTOK)   // 6304
#define PROWS (NIMG*NP2)   // 6272
#define LDK 40             // padded LDS k-stride (bf16 units) = 80B rows

typedef float f32x4 __attribute__((ext_vector_type(4)));
typedef short bf16x8 __attribute__((ext_vector_type(8)));
typedef unsigned short u16x8 __attribute__((ext_vector_type(8)));

__device__ __forceinline__ unsigned short f2bf(float x) {
    unsigned int u = __float_as_uint(x);
    return (unsigned short)((u + 0x7FFFu + ((u >> 16) & 1u)) >> 16);
}
__device__ __forceinline__ float bfhi(unsigned short h) {
    return __uint_as_float(((unsigned int)h) << 16);
}

// ---------------- patchify ----------------
__global__ __launch_bounds__(256) void patchify_kernel(const float* __restrict__ img,
                                                       float* __restrict__ out)
{
    int idx = blockIdx.x * 256 + threadIdx.x;
    if (idx >= PROWS * DIM) return;
    int row = idx / DIM, kk = idx % DIM;
    int b = row / NP2, p = row % NP2;
    int i = p / 14, j = p % 14;
    int c = kk >> 8, r = kk & 255;
    int ph = r >> 4, pw = r & 15;
    out[idx] = img[(((size_t)b*3 + c)*224 + i*16 + ph)*224 + j*16 + pw];
}

// ---------------- class token + pos row0 ----------------
__global__ __launch_bounds__(256) void class_pos_kernel(const float* __restrict__ ct,
                                                        const float* __restrict__ pos,
                                                        float* __restrict__ x)
{
    int idx = blockIdx.x * 256 + threadIdx.x;
    if (idx >= NIMG * DIM) return;
    int b = idx / DIM, d = idx % DIM;
    x[(size_t)b * PTOK * DIM + d] = ct[d] + pos[d];
}

// ---------------- weight conversion: W[K][N] fp32 -> blocked hi/lo bf16 ----------------
// Blocked layout: [N/128][K/32][128][32], i.e. 8KB blocks, row-major [n_in][k_in].
__device__ __forceinline__ void conv_body(const float* __restrict__ W,
    unsigned short* __restrict__ Bh, unsigned short* __restrict__ Bl, int K, int N)
{
    int idx = blockIdx.x * 256 + threadIdx.x;
    if (idx >= N * (K >> 5)) return;
    int kb = idx / N;
    int n  = idx - kb * N;
    size_t off = (((size_t)(n >> 7) * (K >> 5) + kb) * 128 + (n & 127)) * 32;
    #pragma unroll
    for (int u = 0; u < 4; ++u) {
        u16x8 h, l;
        #pragma unroll
        for (int j = 0; j < 8; ++j) {
            float x = W[(size_t)(kb * 32 + u * 8 + j) * N + n];
            unsigned short hh = f2bf(x);
            h[j] = hh;
            l[j] = f2bf(x - bfhi(hh));
        }
        *(u16x8*)&Bh[off + u * 8] = h;
        *(u16x8*)&Bl[off + u * 8] = l;
    }
}

__global__ __launch_bounds__(256) void convert_one(const float* __restrict__ W,
    unsigned short* __restrict__ Bh, unsigned short* __restrict__ Bl, int K, int N)
{
    conv_body(W, Bh, Bl, K, N);
}

__global__ __launch_bounds__(256) void convert_layer(
    const float* __restrict__ qw, const float* __restrict__ mw,
    const float* __restrict__ w1, const float* __restrict__ w2,
    unsigned short* qh, unsigned short* ql, unsigned short* mh, unsigned short* ml,
    unsigned short* h1, unsigned short* l1, unsigned short* h2, unsigned short* l2)
{
    switch (blockIdx.y) {
        case 0: conv_body(qw, qh, ql, DIM, 3*NH*VD); break;
        case 1: conv_body(mw, mh, ml, DIM, DIM);     break;
        case 2: conv_body(w1, h1, l1, DIM, MLPD);    break;
        case 3: conv_body(w2, h2, l2, MLPD, DIM);    break;
    }
}

// ---------------- split-bf16 MFMA GEMM: 128x128 tile, BK=32, 256 thr (4 waves) ----------------
// C = A(fp32,[M][K]) * B(blocked hi/lo bf16) with 3-pass split (hh + hl + lh).
// MODE 1: embed(+pos), 2: qkv scatter, 3: bias+gelu, 4: residual, 5: bias+residual
template<int MODE>
__global__ __launch_bounds__(256, 2) void mgemm(
    const float* __restrict__ A,
    const unsigned short* __restrict__ Bh, const unsigned short* __restrict__ Bl,
    float* __restrict__ C, int M, int N, int K,
    const float* __restrict__ bias, const float* __restrict__ res,
    const float* __restrict__ pos,
    float* __restrict__ qo, float* __restrict__ ko, float* __restrict__ vo)
{
    __shared__ unsigned short AhS[128 * LDK];
    __shared__ unsigned short AlS[128 * LDK];
    __shared__ unsigned short BhS[128 * LDK];
    __shared__ unsigned short BlS[128 * LDK];

    const int tid = threadIdx.x;
    const int m0 = blockIdx.y * 128, n0 = blockIdx.x * 128;
    const int wave = tid >> 6, lane = tid & 63;
    const int wm = (wave >> 1) * 64, wn = (wave & 1) * 64;
    const int lr = lane & 15, lg = lane >> 4;

    // staging mapping: row = tid>>1 (0..127), col half = (tid&1)*16
    const int ar = tid >> 1, ac = (tid & 1) * 16;
    const bool aok = (m0 + ar) < M;
    const float* aP = A + (size_t)(aok ? (m0 + ar) : 0) * K + ac;
    const size_t bBase = ((size_t)(n0 >> 7) * (K >> 5)) * 4096 + (size_t)tid * 16;
    const unsigned short* bhP = Bh + bBase;
    const unsigned short* blP = Bl + bBase;
    const int wOff = ar * LDK + ac;
    const int aOff = (wm + lr) * LDK + lg * 8;
    const int bOff = (wn + lr) * LDK + lg * 8;

    f32x4 acc[4][4];
    #pragma unroll
    for (int i = 0; i < 4; ++i)
        #pragma unroll
        for (int j = 0; j < 4; ++j)
            #pragma unroll
            for (int e = 0; e < 4; ++e) acc[i][j][e] = 0.f;

    f32x4 avr0, avr1, avr2, avr3;
    u16x8 bhr0, bhr1, blr0, blr1;

#define LOAD_REGS(KS) do { \
    const float* _p = aP + (size_t)(KS) * 32; \
    avr0 = *(const f32x4*)(_p);      avr1 = *(const f32x4*)(_p + 4); \
    avr2 = *(const f32x4*)(_p + 8);  avr3 = *(const f32x4*)(_p + 12); \
    const unsigned short* _ph = bhP + (size_t)(KS) * 4096; \
    const unsigned short* _pl = blP + (size_t)(KS) * 4096; \
    bhr0 = *(const u16x8*)(_ph); bhr1 = *(const u16x8*)(_ph + 8); \
    blr0 = *(const u16x8*)(_pl); blr1 = *(const u16x8*)(_pl + 8); \
} while (0)

    const int kSteps = K >> 5;
    LOAD_REGS(0);

    #pragma unroll 1
    for (int ks = 0; ks < kSteps; ++ks) {
        __syncthreads();   // previous iteration's frag reads complete
        {
            u16x8 ahv, alv;
            #pragma unroll
            for (int j = 0; j < 4; ++j) {
                unsigned short hh = f2bf(avr0[j]);
                ahv[j] = hh; alv[j] = f2bf(avr0[j] - bfhi(hh));
            }
            #pragma unroll
            for (int j = 0; j < 4; ++j) {
                unsigned short hh = f2bf(avr1[j]);
                ahv[4 + j] = hh; alv[4 + j] = f2bf(avr1[j] - bfhi(hh));
            }
            *(u16x8*)&AhS[wOff] = ahv;
            *(u16x8*)&AlS[wOff] = alv;
            #pragma unroll
            for (int j = 0; j < 4; ++j) {
                unsigned short hh = f2bf(avr2[j]);
                ahv[j] = hh; alv[j] = f2bf(avr2[j] - bfhi(hh));
            }
            #pragma unroll
            for (int j = 0; j < 4; ++j) {
                unsigned short hh = f2bf(avr3[j]);
                ahv[4 + j] = hh; alv[4 + j] = f2bf(avr3[j] - bfhi(hh));
            }
            *(u16x8*)&AhS[wOff + 8] = ahv;
            *(u16x8*)&AlS[wOff + 8] = alv;
            *(u16x8*)&BhS[wOff] = bhr0;
            *(u16x8*)&BhS[wOff + 8] = bhr1;
            *(u16x8*)&BlS[wOff] = blr0;
            *(u16x8*)&BlS[wOff + 8] = blr1;
        }
        __syncthreads();   // LDS tile visible
        if (ks + 1 < kSteps) LOAD_REGS(ks + 1);   // prefetch hides under MFMA phase

        bf16x8 afh[4], afl[4], bfh[4], bfl[4];
        #pragma unroll
        for (int i = 0; i < 4; ++i) {
            afh[i] = *(const bf16x8*)&AhS[aOff + i * (16 * LDK)];
            afl[i] = *(const bf16x8*)&AlS[aOff + i * (16 * LDK)];
            bfh[i] = *(const bf16x8*)&BhS[bOff + i * (16 * LDK)];
            bfl[i] = *(const bf16x8*)&BlS[bOff + i * (16 * LDK)];
        }
        #pragma unroll
        for (int mi = 0; mi < 4; ++mi)
            #pragma unroll
            for (int ni = 0; ni < 4; ++ni) {
                acc[mi][ni] = __builtin_amdgcn_mfma_f32_16x16x32_bf16(afh[mi], bfh[ni], acc[mi][ni], 0, 0, 0);
                acc[mi][ni] = __builtin_amdgcn_mfma_f32_16x16x32_bf16(afh[mi], bfl[ni], acc[mi][ni], 0, 0, 0);
                acc[mi][ni] = __builtin_amdgcn_mfma_f32_16x16x32_bf16(afl[mi], bfh[ni], acc[mi][ni], 0, 0, 0);
            }
    }
#undef LOAD_REGS

    // epilogue: C[r][c], r = m0+wm+mi*16+lg*4+rr, c = n0+wn+ni*16+lr
    #pragma unroll
    for (int mi = 0; mi < 4; ++mi) {
        #pragma unroll
        for (int ni = 0; ni < 4; ++ni) {
            f32x4 v = acc[mi][ni];
            int c = n0 + wn + ni * 16 + lr;
            #pragma unroll
            for (int rr = 0; rr < 4; ++rr) {
                int r = m0 + wm + mi * 16 + lg * 4 + rr;
                if (r >= M) continue;
                float val = v[rr];
                if (MODE == 1) {
                    int b = r / NP2, p = r - b * NP2;
                    C[((size_t)b * PTOK + 1 + p) * DIM + c] = val + pos[(size_t)(p + 1) * DIM + c];
                } else if (MODE == 2) {
                    int b = r / PTOK, p = r - b * PTOK;
                    int t = c % 3, hv = c / 3;
                    size_t dst = (((size_t)b * NH + (hv >> 6)) * PTOK + p) * VD + (hv & 63);
                    (t == 0 ? qo : t == 1 ? ko : vo)[dst] = val;
                } else if (MODE == 3) {
                    float tmp = val + bias[c];
                    C[(size_t)r * N + c] = 0.5f * tmp * (1.0f + erff(tmp * 0.70710678118654752f));
                } else if (MODE == 4) {
                    C[(size_t)r * N + c] = res[(size_t)r * N + c] + val;
                } else if (MODE == 5) {
                    C[(size_t)r * N + c] = res[(size_t)r * N + c] + val + bias[c];
                }
            }
        }
    }
}

// ---------------- LayerNorm: 1 wave per row ----------------
__global__ __launch_bounds__(256) void ln_kernel(const float* __restrict__ x,
                                                 const float* __restrict__ w,
                                                 const float* __restrict__ b,
                                                 float* __restrict__ out, int rows)
{
    int wave = threadIdx.x >> 6, lane = threadIdx.x & 63;
    int row = blockIdx.x * 4 + wave;
    if (row >= rows) return;
    const float* xr = x + (size_t)row * DIM;
    float vals[12];
    float sum = 0.f;
    #pragma unroll
    for (int u = 0; u < 12; ++u) { vals[u] = xr[u * 64 + lane]; sum += vals[u]; }
    #pragma unroll
    for (int off = 32; off; off >>= 1) sum += __shfl_xor(sum, off);
    float mean = sum * (1.f / DIM);
    float vs = 0.f;
    #pragma unroll
    for (int u = 0; u < 12; ++u) { float d = vals[u] - mean; vs += d * d; }
    #pragma unroll
    for (int off = 32; off; off >>= 1) vs += __shfl_xor(vs, off);
    float rstd = rsqrtf(vs * (1.f / DIM) + 1e-5f);
    float* orow = out + (size_t)row * DIM;
    #pragma unroll
    for (int u = 0; u < 12; ++u) {
        int d = u * 64 + lane;
        orow[d] = (vals[u] - mean) * rstd * w[d] + b[d];
    }
}

// ---------------- fused attention: one block per (bh, 32-row i-tile) ----------------
__global__ __launch_bounds__(256) void attn_kernel(const float* __restrict__ qg,
                                                   const float* __restrict__ kg,
                                                   const float* __restrict__ vg,
                                                   float* __restrict__ og)
{
    __shared__ __align__(16) float klds[104][68];
    __shared__ __align__(16) float qlds[32][68];
    __shared__ __align__(16) float slds[32][200];
    __shared__ float rinv[32];

    const int bh = blockIdx.y;
    const int i0 = blockIdx.x * 32;
    const int b = bh / NH, hh = bh - b * NH;
    const float* qb = qg + (size_t)bh * PTOK * VD;
    const float* kb = kg + (size_t)bh * PTOK * VD;
    const float* vb = vg + (size_t)bh * PTOK * VD;
    const int tid = threadIdx.x;

    for (int idx = tid; idx < 32 * 64; idx += 256) {
        int i = idx >> 6, vv = idx & 63;
        int gi = i0 + i;
        qlds[i][vv] = (gi < PTOK) ? qb[(size_t)gi * VD + vv] : 0.f;
    }

    const int i = tid >> 3, jg = tid & 7;
    float s[25];
    #pragma unroll
    for (int jj = 0; jj < 25; ++jj) s[jj] = -INFINITY;

    for (int chunk = 0; chunk < 2; ++chunk) {
        int jbase = chunk * 104;
        int jcount = (chunk == 0) ? 104 : (PTOK - 104);
        __syncthreads();
        for (int idx = tid; idx < jcount * 64; idx += 256) {
            int j = idx >> 6, vv = idx & 63;
            klds[j][vv] = kb[(size_t)(jbase + j) * VD + vv];
        }
        __syncthreads();
        int jjs = (chunk == 0) ? 0 : 13;
        int jje = (chunk == 0) ? 13 : 25;
        for (int jj = jjs; jj < jje; ++jj) {
            int j = jg + jj * 8;
            if (j >= PTOK) break;
            int jl = j - jbase;
            float acc = 0.f;
            #pragma unroll
            for (int vv = 0; vv < 64; vv += 4) {
                float4 qa = *(const float4*)&qlds[i][vv];
                float4 ka = *(const float4*)&klds[jl][vv];
                acc += qa.x*ka.x + qa.y*ka.y + qa.z*ka.z + qa.w*ka.w;
            }
            s[jj] = acc * 0.125f;
        }
    }

    float m = -INFINITY;
    #pragma unroll
    for (int jj = 0; jj < 25; ++jj) m = fmaxf(m, s[jj]);
    #pragma unroll
    for (int off = 1; off < 8; off <<= 1) m = fmaxf(m, __shfl_xor(m, off));
    float sum = 0.f;
    #pragma unroll
    for (int jj = 0; jj < 25; ++jj) {
        int j = jg + jj * 8;
        float p = (s[jj] == -INFINITY) ? 0.f : expf(s[jj] - m);
        if (j < PTOK) slds[i][j] = p;
        sum += p;
    }
    #pragma unroll
    for (int off = 1; off < 8; off <<= 1) sum += __shfl_xor(sum, off);
    if (jg == 0) rinv[i] = 1.f / sum;
    __syncthreads();

    const int vv = tid & 63, ig = tid >> 6;
    float accv[8] = {};
    for (int j4 = 0; j4 < 196; j4 += 4) {
        float v0 = vb[(size_t)(j4 + 0) * VD + vv];
        float v1 = vb[(size_t)(j4 + 1) * VD + vv];
        float v2 = vb[(size_t)(j4 + 2) * VD + vv];
        float v3 = vb[(size_t)(j4 + 3) * VD + vv];
        #pragma unroll
        for (int u = 0; u < 8; ++u) {
            float4 sv = *(const float4*)&slds[ig * 8 + u][j4];
            accv[u] += sv.x * v0 + sv.y * v1 + sv.z * v2 + sv.w * v3;
        }
    }
    {
        float v0 = vb[(size_t)196 * VD + vv];
        #pragma unroll
        for (int u = 0; u < 8; ++u) accv[u] += slds[ig * 8 + u][196] * v0;
    }
    #pragma unroll
    for (int u = 0; u < 8; ++u) {
        int i2 = ig * 8 + u, gi = i0 + i2;
        if (gi < PTOK)
            og[((size_t)b * PTOK + gi) * DIM + hh * VD + vv] = accv[u] * rinv[i2];
    }
}

// ---------------- head: logits + softmax, one block per image ----------------
__global__ __launch_bounds__(256) void head_kernel(const float* __restrict__ x,
                                                   const float* __restrict__ W,
                                                   const float* __restrict__ bias,
                                                   float* __restrict__ out)
{
    __shared__ __align__(16) float xl[DIM];
    __shared__ float red[4];
    int b = blockIdx.x;
    const float* xr = x + (size_t)b * PTOK * DIM;
    for (int idx = threadIdx.x; idx < DIM; idx += 256) xl[idx] = xr[idx];
    __syncthreads();

    float logit[4];
    #pragma unroll
    for (int u = 0; u < 4; ++u) {
        int c = threadIdx.x + u * 256;
        float acc = (c < 1000) ? bias[c] : -INFINITY;
        if (c < 1000) {
            for (int k = 0; k < DIM; k += 4) {
                float4 xv = *(const float4*)&xl[k];
                acc += xv.x * W[(size_t)k * 1000 + c]
                     + xv.y * W[(size_t)(k + 1) * 1000 + c]
                     + xv.z * W[(size_t)(k + 2) * 1000 + c]
                     + xv.w * W[(size_t)(k + 3) * 1000 + c];
            }
        }
        logit[u] = acc;
    }
    int lane = threadIdx.x & 63, wv = threadIdx.x >> 6;
    float m = fmaxf(fmaxf(logit[0], logit[1]), fmaxf(logit[2], logit[3]));
    #pragma unroll
    for (int off = 32; off; off >>= 1) m = fmaxf(m, __shfl_xor(m, off));
    if (lane == 0) red[wv] = m;
    __syncthreads();
    m = fmaxf(fmaxf(red[0], red[1]), fmaxf(red[2], red[3]));

    float p[4]; float sum = 0.f;
    #pragma unroll
    for (int u = 0; u < 4; ++u) {
        int c = threadIdx.x + u * 256;
        p[u] = (c < 1000) ? expf(logit[u] - m) : 0.f;
        sum += p[u];
    }
    #pragma unroll
    for (int off = 32; off; off >>= 1) sum += __shfl_xor(sum, off);
    __syncthreads();
    if (lane == 0) red[wv] = sum;
    __syncthreads();
    float inv = 1.f / (red[0] + red[1] + red[2] + red[3]);
    #pragma unroll
    for (int u = 0; u < 4; ++u) {
        int c = threadIdx.x + u * 256;
        if (c < 1000) out[(size_t)b * 1000 + c] = p[u] * inv;
    }
}

// ---------------- launcher ----------------
extern "C" void kernel_launch(void* const* d_in, const int* in_sizes, int n_in,
                              void* d_out, int out_size, void* d_ws, size_t ws_size,
                              hipStream_t stream)
{
    const float* images  = (const float*)d_in[0];
    const float* W_map   = (const float*)d_in[1];
    const float* ct      = (const float*)d_in[2];
    const float* pos     = (const float*)d_in[3];
    const float* ln1_w   = (const float*)d_in[4];
    const float* ln1_b   = (const float*)d_in[5];
    const float* qkv_w   = (const float*)d_in[6];
    const float* merge_w = (const float*)d_in[7];
    const float* ln2_w   = (const float*)d_in[8];
    const float* ln2_b   = (const float*)d_in[9];
    const float* mlp_w1  = (const float*)d_in[10];
    const float* mlp_b1  = (const float*)d_in[11];
    const float* mlp_w2  = (const float*)d_in[12];
    const float* mlp_b2  = (const float*)d_in[13];
    const float* head_w  = (const float*)d_in[14];
    const float* head_b  = (const float*)d_in[15];
    float* out = (float*)d_out;

    float* ws = (float*)d_ws;
    const size_t XE = (size_t)ROWS * DIM;
    float* x  = ws;
    float* h  = x  + XE;
    float* qb = h  + XE;
    float* kb = qb + XE;
    float* vb = kb + XE;
    float* ob = vb + XE;
    float* g  = ob + XE;                    // ROWS*MLPD
    float* patches = g;                     // alias: used only before g is written

    // per-layer weight hi/lo buffers (ushort), after g
    unsigned short* wb = (unsigned short*)(g + (size_t)ROWS * MLPD);
    const size_t qkvE = (size_t)DIM * 2304;
    const size_t mgE  = (size_t)DIM * DIM;
    const size_t m1E  = (size_t)DIM * MLPD;
    const size_t m2E  = (size_t)MLPD * DIM;
    unsigned short* qh  = wb;
    unsigned short* ql  = qh  + qkvE;
    unsigned short* mh  = ql  + qkvE;
    unsigned short* ml  = mh  + mgE;
    unsigned short* h1  = ml  + mgE;
    unsigned short* l1  = h1  + m1E;
    unsigned short* h2  = l1  + m1E;
    unsigned short* l2  = h2  + m2E;
    unsigned short* wmh = l2  + m2E;
    unsigned short* wml = wmh + mgE;

    patchify_kernel<<<(PROWS * DIM + 255) / 256, 256, 0, stream>>>(images, patches);
    class_pos_kernel<<<(NIMG * DIM + 255) / 256, 256, 0, stream>>>(ct, pos, x);
    convert_one<<<(DIM * (DIM / 32) + 255) / 256, 256, 0, stream>>>(W_map, wmh, wml, DIM, DIM);
    mgemm<1><<<dim3(DIM / 128, PROWS / 128), 256, 0, stream>>>(
        patches, wmh, wml, x, PROWS, DIM, DIM, nullptr, nullptr, pos, nullptr, nullptr, nullptr);

    const int mblk = (ROWS + 127) / 128;  // 50
    for (int l = 0; l < 12; ++l) {
        convert_layer<<<dim3(288, 4), 256, 0, stream>>>(
            qkv_w + (size_t)l * qkvE, merge_w + (size_t)l * mgE,
            mlp_w1 + (size_t)l * m1E, mlp_w2 + (size_t)l * m2E,
            qh, ql, mh, ml, h1, l1, h2, l2);
        ln_kernel<<<(ROWS + 3) / 4, 256, 0, stream>>>(x, ln1_w + l * DIM, ln1_b + l * DIM, h, ROWS);
        mgemm<2><<<dim3(2304 / 128, mblk), 256, 0, stream>>>(
            h, qh, ql, nullptr, ROWS, 2304, DIM, nullptr, nullptr, nullptr, qb, kb, vb);
        attn_kernel<<<dim3(7, NIMG * NH), 256, 0, stream>>>(qb, kb, vb, ob);
        mgemm<4><<<dim3(DIM / 128, mblk), 256, 0, stream>>>(
            ob, mh, ml, x, ROWS, DIM, DIM, nullptr, x, nullptr, nullptr, nullptr, nullptr);
        ln_kernel<<<(ROWS + 3) / 4, 256, 0, stream>>>(x, ln2_w + l * DIM, ln2_b + l * DIM, h, ROWS);
        mgemm<3><<<dim3(MLPD / 128, mblk), 256, 0, stream>>>(
            h, h1, l1, g, ROWS, MLPD, DIM, mlp_b1 + (size_t)l * MLPD, nullptr, nullptr, nullptr, nullptr, nullptr);
        mgemm<5><<<dim3(DIM / 128, mblk), 256, 0, stream>>>(
            g, h2, l2, x, ROWS, DIM, MLPD, mlp_b2 + (size_t)l * DIM, x, nullptr, nullptr, nullptr, nullptr);
    }
    head_kernel<<<NIMG, 256, 0, stream>>>(x, head_w, head_b, out);
}

// Round 3
// 6436.057 us; speedup vs baseline: 2.7996x; 1.3410x over previous
//
#include <hip/hip_runtime.h>
#include <math.h>

// ---------------- constants ----------------
#define NIMG 32
#define NP2  196        // patches per image
#define PTOK 197        // tokens per image
#define DIM  768
#define NH   12
#define VD   64
#define MLPD 3072
#define ROWS (NIMG*PTOK)   // 6304
#define PROWS (NIMG*NP2)   // 6272
#define LDK 40             // padded LDS k-stride (bf16 units) = 80B rows
#define PSTR 208           // padded token stride for q/k/v planes
#define BHN (NIMG*NH)      // 384

typedef float f32x4 __attribute__((ext_vector_type(4)));
typedef short bf16x8 __attribute__((ext_vector_type(8)));
typedef unsigned short u16x8 __attribute__((ext_vector_type(8)));
typedef unsigned short u16x4 __attribute__((ext_vector_type(4)));

__device__ __forceinline__ unsigned short f2bf(float x) {
    unsigned int u = __float_as_uint(x);
    return (unsigned short)((u + 0x7FFFu + ((u >> 16) & 1u)) >> 16);
}
__device__ __forceinline__ float bfhi(unsigned short h) {
    return __uint_as_float(((unsigned int)h) << 16);
}

// ---------------- patchify ----------------
__global__ __launch_bounds__(256) void patchify_kernel(const float* __restrict__ img,
                                                       float* __restrict__ out)
{
    int idx = blockIdx.x * 256 + threadIdx.x;
    if (idx >= PROWS * DIM) return;
    int row = idx / DIM, kk = idx % DIM;
    int b = row / NP2, p = row % NP2;
    int i = p / 14, j = p % 14;
    int c = kk >> 8, r = kk & 255;
    int ph = r >> 4, pw = r & 15;
    out[idx] = img[(((size_t)b*3 + c)*224 + i*16 + ph)*224 + j*16 + pw];
}

// ---------------- class token + pos row0 ----------------
__global__ __launch_bounds__(256) void class_pos_kernel(const float* __restrict__ ct,
                                                        const float* __restrict__ pos,
                                                        float* __restrict__ x)
{
    int idx = blockIdx.x * 256 + threadIdx.x;
    if (idx >= NIMG * DIM) return;
    int b = idx / DIM, d = idx % DIM;
    x[(size_t)b * PTOK * DIM + d] = ct[d] + pos[d];
}

// ---------------- weight conversion: W[K][N] fp32 -> blocked hi/lo bf16 ----------------
__device__ __forceinline__ void conv_body(const float* __restrict__ W,
    unsigned short* __restrict__ Bh, unsigned short* __restrict__ Bl, int K, int N)
{
    int idx = blockIdx.x * 256 + threadIdx.x;
    if (idx >= N * (K >> 5)) return;
    int kb = idx / N;
    int n  = idx - kb * N;
    size_t off = (((size_t)(n >> 7) * (K >> 5) + kb) * 128 + (n & 127)) * 32;
    #pragma unroll
    for (int u = 0; u < 4; ++u) {
        u16x8 h, l;
        #pragma unroll
        for (int j = 0; j < 8; ++j) {
            float x = W[(size_t)(kb * 32 + u * 8 + j) * N + n];
            unsigned short hh = f2bf(x);
            h[j] = hh;
            l[j] = f2bf(x - bfhi(hh));
        }
        *(u16x8*)&Bh[off + u * 8] = h;
        *(u16x8*)&Bl[off + u * 8] = l;
    }
}

__global__ __launch_bounds__(256) void convert_one(const float* __restrict__ W,
    unsigned short* __restrict__ Bh, unsigned short* __restrict__ Bl, int K, int N)
{
    conv_body(W, Bh, Bl, K, N);
}

__global__ __launch_bounds__(256) void convert_layer(
    const float* __restrict__ qw, const float* __restrict__ mw,
    const float* __restrict__ w1, const float* __restrict__ w2,
    unsigned short* qh, unsigned short* ql, unsigned short* mh, unsigned short* ml,
    unsigned short* h1, unsigned short* l1, unsigned short* h2, unsigned short* l2)
{
    switch (blockIdx.y) {
        case 0: conv_body(qw, qh, ql, DIM, 3*NH*VD); break;
        case 1: conv_body(mw, mh, ml, DIM, DIM);     break;
        case 2: conv_body(w1, h1, l1, DIM, MLPD);    break;
        case 3: conv_body(w2, h2, l2, MLPD, DIM);    break;
    }
}

// ---------------- split-bf16 MFMA GEMM: 128x128 tile, BK=32, 256 thr ----------------
// MODE 1: embed(+pos), 2: qkv -> packed hi/lo planes, 3: bias+gelu, 4: residual, 5: bias+residual
template<int MODE>
__global__ __launch_bounds__(256, 2) void mgemm(
    const float* __restrict__ A,
    const unsigned short* __restrict__ Bh, const unsigned short* __restrict__ Bl,
    float* __restrict__ C, int M, int N, int K,
    const float* __restrict__ bias, const float* __restrict__ res,
    const float* __restrict__ pos,
    unsigned int* __restrict__ qo, unsigned int* __restrict__ ko, unsigned int* __restrict__ vo)
{
    __shared__ unsigned short AhS[128 * LDK];
    __shared__ unsigned short AlS[128 * LDK];
    __shared__ unsigned short BhS[128 * LDK];
    __shared__ unsigned short BlS[128 * LDK];

    const int tid = threadIdx.x;
    const int m0 = blockIdx.y * 128, n0 = blockIdx.x * 128;
    const int wave = tid >> 6, lane = tid & 63;
    const int wm = (wave >> 1) * 64, wn = (wave & 1) * 64;
    const int lr = lane & 15, lg = lane >> 4;

    const int ar = tid >> 1, ac = (tid & 1) * 16;
    const bool aok = (m0 + ar) < M;
    const float* aP = A + (size_t)(aok ? (m0 + ar) : 0) * K + ac;
    const size_t bBase = ((size_t)(n0 >> 7) * (K >> 5)) * 4096 + (size_t)tid * 16;
    const unsigned short* bhP = Bh + bBase;
    const unsigned short* blP = Bl + bBase;
    const int wOff = ar * LDK + ac;
    const int aOff = (wm + lr) * LDK + lg * 8;
    const int bOff = (wn + lr) * LDK + lg * 8;

    f32x4 acc[4][4];
    #pragma unroll
    for (int i = 0; i < 4; ++i)
        #pragma unroll
        for (int j = 0; j < 4; ++j)
            #pragma unroll
            for (int e = 0; e < 4; ++e) acc[i][j][e] = 0.f;

    f32x4 avr0, avr1, avr2, avr3;
    u16x8 bhr0, bhr1, blr0, blr1;

#define LOAD_REGS(KS) do { \
    const float* _p = aP + (size_t)(KS) * 32; \
    avr0 = *(const f32x4*)(_p);      avr1 = *(const f32x4*)(_p + 4); \
    avr2 = *(const f32x4*)(_p + 8);  avr3 = *(const f32x4*)(_p + 12); \
    const unsigned short* _ph = bhP + (size_t)(KS) * 4096; \
    const unsigned short* _pl = blP + (size_t)(KS) * 4096; \
    bhr0 = *(const u16x8*)(_ph); bhr1 = *(const u16x8*)(_ph + 8); \
    blr0 = *(const u16x8*)(_pl); blr1 = *(const u16x8*)(_pl + 8); \
} while (0)

    const int kSteps = K >> 5;
    LOAD_REGS(0);

    #pragma unroll 1
    for (int ks = 0; ks < kSteps; ++ks) {
        __syncthreads();
        {
            u16x8 ahv, alv;
            #pragma unroll
            for (int j = 0; j < 4; ++j) {
                unsigned short hh = f2bf(avr0[j]);
                ahv[j] = hh; alv[j] = f2bf(avr0[j] - bfhi(hh));
            }
            #pragma unroll
            for (int j = 0; j < 4; ++j) {
                unsigned short hh = f2bf(avr1[j]);
                ahv[4 + j] = hh; alv[4 + j] = f2bf(avr1[j] - bfhi(hh));
            }
            *(u16x8*)&AhS[wOff] = ahv;
            *(u16x8*)&AlS[wOff] = alv;
            #pragma unroll
            for (int j = 0; j < 4; ++j) {
                unsigned short hh = f2bf(avr2[j]);
                ahv[j] = hh; alv[j] = f2bf(avr2[j] - bfhi(hh));
            }
            #pragma unroll
            for (int j = 0; j < 4; ++j) {
                unsigned short hh = f2bf(avr3[j]);
                ahv[4 + j] = hh; alv[4 + j] = f2bf(avr3[j] - bfhi(hh));
            }
            *(u16x8*)&AhS[wOff + 8] = ahv;
            *(u16x8*)&AlS[wOff + 8] = alv;
            *(u16x8*)&BhS[wOff] = bhr0;
            *(u16x8*)&BhS[wOff + 8] = bhr1;
            *(u16x8*)&BlS[wOff] = blr0;
            *(u16x8*)&BlS[wOff + 8] = blr1;
        }
        __syncthreads();
        if (ks + 1 < kSteps) LOAD_REGS(ks + 1);

        bf16x8 afh[4], afl[4], bfh[4], bfl[4];
        #pragma unroll
        for (int i = 0; i < 4; ++i) {
            afh[i] = *(const bf16x8*)&AhS[aOff + i * (16 * LDK)];
            afl[i] = *(const bf16x8*)&AlS[aOff + i * (16 * LDK)];
            bfh[i] = *(const bf16x8*)&BhS[bOff + i * (16 * LDK)];
            bfl[i] = *(const bf16x8*)&BlS[bOff + i * (16 * LDK)];
        }
        #pragma unroll
        for (int mi = 0; mi < 4; ++mi)
            #pragma unroll
            for (int ni = 0; ni < 4; ++ni) {
                acc[mi][ni] = __builtin_amdgcn_mfma_f32_16x16x32_bf16(afh[mi], bfh[ni], acc[mi][ni], 0, 0, 0);
                acc[mi][ni] = __builtin_amdgcn_mfma_f32_16x16x32_bf16(afh[mi], bfl[ni], acc[mi][ni], 0, 0, 0);
                acc[mi][ni] = __builtin_amdgcn_mfma_f32_16x16x32_bf16(afl[mi], bfh[ni], acc[mi][ni], 0, 0, 0);
            }
    }
#undef LOAD_REGS

    #pragma unroll
    for (int mi = 0; mi < 4; ++mi) {
        #pragma unroll
        for (int ni = 0; ni < 4; ++ni) {
            f32x4 v = acc[mi][ni];
            int c = n0 + wn + ni * 16 + lr;
            #pragma unroll
            for (int rr = 0; rr < 4; ++rr) {
                int r = m0 + wm + mi * 16 + lg * 4 + rr;
                if (r >= M) continue;
                float val = v[rr];
                if (MODE == 1) {
                    int b = r / NP2, p = r - b * NP2;
                    C[((size_t)b * PTOK + 1 + p) * DIM + c] = val + pos[(size_t)(p + 1) * DIM + c];
                } else if (MODE == 2) {
                    int b = r / PTOK, p = r - b * PTOK;
                    int t = c % 3, hv = c / 3;
                    int hd = hv >> 6, vv = hv & 63;
                    size_t bh = (size_t)b * NH + hd;
                    float sv = (t == 0) ? val * 0.125f : val;
                    unsigned short hi = f2bf(sv);
                    unsigned short lo = f2bf(sv - bfhi(hi));
                    unsigned int w32 = (unsigned int)hi | ((unsigned int)lo << 16);
                    if (t == 2) vo[(bh * 64 + vv) * PSTR + p] = w32;
                    else if (t == 0) qo[(bh * PSTR + p) * 64 + vv] = w32;
                    else ko[(bh * PSTR + p) * 64 + vv] = w32;
                } else if (MODE == 3) {
                    float tmp = val + bias[c];
                    C[(size_t)r * N + c] = 0.5f * tmp * (1.0f + erff(tmp * 0.70710678118654752f));
                } else if (MODE == 4) {
                    C[(size_t)r * N + c] = res[(size_t)r * N + c] + val;
                } else if (MODE == 5) {
                    C[(size_t)r * N + c] = res[(size_t)r * N + c] + val + bias[c];
                }
            }
        }
    }
}

// ---------------- LayerNorm ----------------
__global__ __launch_bounds__(256) void ln_kernel(const float* __restrict__ x,
                                                 const float* __restrict__ w,
                                                 const float* __restrict__ b,
                                                 float* __restrict__ out, int rows)
{
    int wave = threadIdx.x >> 6, lane = threadIdx.x & 63;
    int row = blockIdx.x * 4 + wave;
    if (row >= rows) return;
    const float* xr = x + (size_t)row * DIM;
    float vals[12];
    float sum = 0.f;
    #pragma unroll
    for (int u = 0; u < 12; ++u) { vals[u] = xr[u * 64 + lane]; sum += vals[u]; }
    #pragma unroll
    for (int off = 32; off; off >>= 1) sum += __shfl_xor(sum, off);
    float mean = sum * (1.f / DIM);
    float vs = 0.f;
    #pragma unroll
    for (int u = 0; u < 12; ++u) { float d = vals[u] - mean; vs += d * d; }
    #pragma unroll
    for (int off = 32; off; off >>= 1) vs += __shfl_xor(vs, off);
    float rstd = rsqrtf(vs * (1.f / DIM) + 1e-5f);
    float* orow = out + (size_t)row * DIM;
    #pragma unroll
    for (int u = 0; u < 12; ++u) {
        int d = u * 64 + lane;
        orow[d] = (vals[u] - mean) * rstd * w[d] + b[d];
    }
}

// ---------------- MFMA attention: block = (q-tile 64, bh), 4 waves ----------------
// Q/K planes: packed u32 (lo<<16|hi) [bh][PSTR][64]; V^T plane: [bh][64][PSTR].
// 3-pass split-bf16 for QK^T and PV. Softmax fp32 in registers.
__global__ __launch_bounds__(256) void attn_mfma(
    const unsigned int* __restrict__ qp, const unsigned int* __restrict__ kp,
    const unsigned int* __restrict__ vtp, float* __restrict__ og)
{
    __shared__ unsigned short KVh[64 * 72];
    __shared__ unsigned short KVl[64 * 72];
    __shared__ unsigned short Ph[64 * 72];
    __shared__ unsigned short Pl[64 * 72];

    const int tid = threadIdx.x;
    const int w = tid >> 6, lane = tid & 63;
    const int l = lane & 15, g = lane >> 4;
    const int bh = blockIdx.y, q0 = blockIdx.x * 64;
    const int b = bh / NH, hd = bh - b * NH;

    // ---- Q fragments (registers, reused across all chunks) ----
    int qrow = q0 + 16 * w + l;
    if (qrow >= PTOK) qrow = 0;              // masked at output
    const unsigned int* qbase = qp + ((size_t)bh * PSTR + qrow) * 64;
    bf16x8 qAh[2], qAl[2];
    #pragma unroll
    for (int ks = 0; ks < 2; ++ks) {
        const unsigned int* p = qbase + 32 * ks + 8 * g;
        uint4 a = *(const uint4*)p;
        uint4 c = *(const uint4*)(p + 4);
        bf16x8 h8, l8;
        h8[0]=(short)a.x; h8[1]=(short)a.y; h8[2]=(short)a.z; h8[3]=(short)a.w;
        h8[4]=(short)c.x; h8[5]=(short)c.y; h8[6]=(short)c.z; h8[7]=(short)c.w;
        l8[0]=(short)(a.x>>16); l8[1]=(short)(a.y>>16); l8[2]=(short)(a.z>>16); l8[3]=(short)(a.w>>16);
        l8[4]=(short)(c.x>>16); l8[5]=(short)(c.y>>16); l8[6]=(short)(c.z>>16); l8[7]=(short)(c.w>>16);
        qAh[ks] = h8; qAl[ks] = l8;
    }

    f32x4 s[13];
    #pragma unroll
    for (int t = 0; t < 13; ++t)
        #pragma unroll
        for (int e = 0; e < 4; ++e) s[t][e] = 0.f;

    // ---- loop 1: S = QK^T over 4 j-chunks ----
    for (int c = 0; c < 4; ++c) {
        __syncthreads();
        const int rows = (c < 3) ? 64 : 16;
        for (int u = tid; u < rows * 16; u += 256) {
            int r = u >> 4, cc = u & 15;
            int j = c * 64 + r;
            uint4 wv = make_uint4(0, 0, 0, 0);
            if (j < PTOK) wv = *(const uint4*)(kp + ((size_t)bh * PSTR + j) * 64 + cc * 4);
            u16x4 h4, l4;
            h4[0]=(unsigned short)wv.x; h4[1]=(unsigned short)wv.y;
            h4[2]=(unsigned short)wv.z; h4[3]=(unsigned short)wv.w;
            l4[0]=(unsigned short)(wv.x>>16); l4[1]=(unsigned short)(wv.y>>16);
            l4[2]=(unsigned short)(wv.z>>16); l4[3]=(unsigned short)(wv.w>>16);
            *(u16x4*)&KVh[r * 72 + cc * 4] = h4;
            *(u16x4*)&KVl[r * 72 + cc * 4] = l4;
        }
        __syncthreads();
        const int tc = (c < 3) ? 4 : 1;
        for (int t = 0; t < tc; ++t) {
            int ti = c * 4 + t;
            #pragma unroll
            for (int ks = 0; ks < 2; ++ks) {
                bf16x8 kh = *(const bf16x8*)&KVh[(16 * t + l) * 72 + 32 * ks + 8 * g];
                bf16x8 kl = *(const bf16x8*)&KVl[(16 * t + l) * 72 + 32 * ks + 8 * g];
                s[ti] = __builtin_amdgcn_mfma_f32_16x16x32_bf16(qAh[ks], kh, s[ti], 0, 0, 0);
                s[ti] = __builtin_amdgcn_mfma_f32_16x16x32_bf16(qAh[ks], kl, s[ti], 0, 0, 0);
                s[ti] = __builtin_amdgcn_mfma_f32_16x16x32_bf16(qAl[ks], kh, s[ti], 0, 0, 0);
            }
        }
    }

    // mask padded j (tile 12 covers j=192+l; valid only l<5)
    if (l >= 5) {
        #pragma unroll
        for (int e = 0; e < 4; ++e) s[12][e] = -1e30f;
    }

    // ---- softmax (rows distributed: row q = 16w + 4g + e, cols across 16 lanes) ----
    float mx[4], rs[4];
    #pragma unroll
    for (int e = 0; e < 4; ++e) {
        float m = s[0][e];
        #pragma unroll
        for (int t = 1; t < 13; ++t) m = fmaxf(m, s[t][e]);
        #pragma unroll
        for (int off = 1; off < 16; off <<= 1) m = fmaxf(m, __shfl_xor(m, off));
        mx[e] = m;
    }
    #pragma unroll
    for (int e = 0; e < 4; ++e) {
        float sum = 0.f;
        #pragma unroll
        for (int t = 0; t < 13; ++t) {
            float p = __expf(s[t][e] - mx[e]);
            s[t][e] = p;
            sum += p;
        }
        #pragma unroll
        for (int off = 1; off < 16; off <<= 1) sum += __shfl_xor(sum, off);
        rs[e] = 1.f / sum;
    }

    // ---- loop 2: O = P V over 4 j-chunks (V^T staged into KV buffers) ----
    f32x4 o[4];
    #pragma unroll
    for (int t = 0; t < 4; ++t)
        #pragma unroll
        for (int e = 0; e < 4; ++e) o[t][e] = 0.f;

    for (int c = 0; c < 4; ++c) {
        __syncthreads();
        const int cols = (c < 3) ? 64 : 32;   // chunk-3: stage 32 cols (zeros past 196)
        const int cpr = cols >> 2;            // 16B units per row
        for (int u = tid; u < 64 * cpr; u += 256) {
            int r = u / cpr, cc = u % cpr;
            int jbase = c * 64 + cc * 4;
            uint4 wv;
            if (c < 3) {
                wv = *(const uint4*)(vtp + ((size_t)bh * 64 + r) * PSTR + jbase);
            } else {
                unsigned int t0 = (jbase + 0 < PTOK) ? vtp[((size_t)bh * 64 + r) * PSTR + jbase + 0] : 0u;
                unsigned int t1 = (jbase + 1 < PTOK) ? vtp[((size_t)bh * 64 + r) * PSTR + jbase + 1] : 0u;
                unsigned int t2 = (jbase + 2 < PTOK) ? vtp[((size_t)bh * 64 + r) * PSTR + jbase + 2] : 0u;
                unsigned int t3 = (jbase + 3 < PTOK) ? vtp[((size_t)bh * 64 + r) * PSTR + jbase + 3] : 0u;
                wv = make_uint4(t0, t1, t2, t3);
            }
            u16x4 h4, l4;
            h4[0]=(unsigned short)wv.x; h4[1]=(unsigned short)wv.y;
            h4[2]=(unsigned short)wv.z; h4[3]=(unsigned short)wv.w;
            l4[0]=(unsigned short)(wv.x>>16); l4[1]=(unsigned short)(wv.y>>16);
            l4[2]=(unsigned short)(wv.z>>16); l4[3]=(unsigned short)(wv.w>>16);
            *(u16x4*)&KVh[r * 72 + cc * 4] = h4;
            *(u16x4*)&KVl[r * 72 + cc * 4] = l4;
        }
        // write this chunk's P (hi/lo bf16) — wave-local rows, no cross-wave dep
        const int tc = (c < 3) ? 4 : 1;
        for (int t = 0; t < tc; ++t) {
            int ti = c * 4 + t;
            #pragma unroll
            for (int e = 0; e < 4; ++e) {
                int row = 16 * w + 4 * g + e, col = 16 * t + l;
                float pv = s[ti][e];
                unsigned short hi = f2bf(pv);
                Ph[row * 72 + col] = hi;
                Pl[row * 72 + col] = f2bf(pv - bfhi(hi));
            }
        }
        __syncthreads();
        const int ksn = (c < 3) ? 2 : 1;
        for (int ks = 0; ks < ksn; ++ks) {
            bf16x8 pa_h = *(const bf16x8*)&Ph[(16 * w + l) * 72 + 32 * ks + 8 * g];
            bf16x8 pa_l = *(const bf16x8*)&Pl[(16 * w + l) * 72 + 32 * ks + 8 * g];
            #pragma unroll
            for (int tv = 0; tv < 4; ++tv) {
                bf16x8 vh = *(const bf16x8*)&KVh[(16 * tv + l) * 72 + 32 * ks + 8 * g];
                bf16x8 vl = *(const bf16x8*)&KVl[(16 * tv + l) * 72 + 32 * ks + 8 * g];
                o[tv] = __builtin_amdgcn_mfma_f32_16x16x32_bf16(pa_h, vh, o[tv], 0, 0, 0);
                o[tv] = __builtin_amdgcn_mfma_f32_16x16x32_bf16(pa_h, vl, o[tv], 0, 0, 0);
                o[tv] = __builtin_amdgcn_mfma_f32_16x16x32_bf16(pa_l, vh, o[tv], 0, 0, 0);
            }
        }
    }

    // ---- epilogue: og[b][q][hd*64+v] = o * rs ----
    #pragma unroll
    for (int tv = 0; tv < 4; ++tv) {
        #pragma unroll
        for (int e = 0; e < 4; ++e) {
            int q = q0 + 16 * w + 4 * g + e;
            if (q < PTOK)
                og[((size_t)(b * PTOK + q)) * DIM + hd * 64 + 16 * tv + l] = o[tv][e] * rs[e];
        }
    }
}

// ---------------- head: logits + softmax ----------------
__global__ __launch_bounds__(256) void head_kernel(const float* __restrict__ x,
                                                   const float* __restrict__ W,
                                                   const float* __restrict__ bias,
                                                   float* __restrict__ out)
{
    __shared__ __align__(16) float xl[DIM];
    __shared__ float red[4];
    int b = blockIdx.x;
    const float* xr = x + (size_t)b * PTOK * DIM;
    for (int idx = threadIdx.x; idx < DIM; idx += 256) xl[idx] = xr[idx];
    __syncthreads();

    float logit[4];
    #pragma unroll
    for (int u = 0; u < 4; ++u) {
        int c = threadIdx.x + u * 256;
        float acc = (c < 1000) ? bias[c] : -INFINITY;
        if (c < 1000) {
            for (int k = 0; k < DIM; k += 4) {
                float4 xv = *(const float4*)&xl[k];
                acc += xv.x * W[(size_t)k * 1000 + c]
                     + xv.y * W[(size_t)(k + 1) * 1000 + c]
                     + xv.z * W[(size_t)(k + 2) * 1000 + c]
                     + xv.w * W[(size_t)(k + 3) * 1000 + c];
            }
        }
        logit[u] = acc;
    }
    int lane = threadIdx.x & 63, wv = threadIdx.x >> 6;
    float m = fmaxf(fmaxf(logit[0], logit[1]), fmaxf(logit[2], logit[3]));
    #pragma unroll
    for (int off = 32; off; off >>= 1) m = fmaxf(m, __shfl_xor(m, off));
    if (lane == 0) red[wv] = m;
    __syncthreads();
    m = fmaxf(fmaxf(red[0], red[1]), fmaxf(red[2], red[3]));

    float p[4]; float sum = 0.f;
    #pragma unroll
    for (int u = 0; u < 4; ++u) {
        int c = threadIdx.x + u * 256;
        p[u] = (c < 1000) ? expf(logit[u] - m) : 0.f;
        sum += p[u];
    }
    #pragma unroll
    for (int off = 32; off; off >>= 1) sum += __shfl_xor(sum, off);
    __syncthreads();
    if (lane == 0) red[wv] = sum;
    __syncthreads();
    float inv = 1.f / (red[0] + red[1] + red[2] + red[3]);
    #pragma unroll
    for (int u = 0; u < 4; ++u) {
        int c = threadIdx.x + u * 256;
        if (c < 1000) out[(size_t)b * 1000 + c] = p[u] * inv;
    }
}

// ---------------- launcher ----------------
extern "C" void kernel_launch(void* const* d_in, const int* in_sizes, int n_in,
                              void* d_out, int out_size, void* d_ws, size_t ws_size,
                              hipStream_t stream)
{
    const float* images  = (const float*)d_in[0];
    const float* W_map   = (const float*)d_in[1];
    const float* ct      = (const float*)d_in[2];
    const float* pos     = (const float*)d_in[3];
    const float* ln1_w   = (const float*)d_in[4];
    const float* ln1_b   = (const float*)d_in[5];
    const float* qkv_w   = (const float*)d_in[6];
    const float* merge_w = (const float*)d_in[7];
    const float* ln2_w   = (const float*)d_in[8];
    const float* ln2_b   = (const float*)d_in[9];
    const float* mlp_w1  = (const float*)d_in[10];
    const float* mlp_b1  = (const float*)d_in[11];
    const float* mlp_w2  = (const float*)d_in[12];
    const float* mlp_b2  = (const float*)d_in[13];
    const float* head_w  = (const float*)d_in[14];
    const float* head_b  = (const float*)d_in[15];
    float* out = (float*)d_out;

    float* ws = (float*)d_ws;
    const size_t XE = (size_t)ROWS * DIM;
    float* x  = ws;
    float* h  = x  + XE;
    float* ob = h  + XE;
    float* g  = ob + XE;                    // ROWS*MLPD floats

    // q/k/v packed planes alias g (lifetimes disjoint within a layer)
    const size_t PL = (size_t)BHN * PSTR * 64;     // 5,111,808 u32
    unsigned int* qpl = (unsigned int*)g;
    unsigned int* kpl = qpl + PL;
    unsigned int* vtp = kpl + PL;
    float* patches = g;                     // used only before first qkv

    // weight hi/lo planes after g
    unsigned short* wb = (unsigned short*)(g + (size_t)ROWS * MLPD);
    const size_t qkvE = (size_t)DIM * 2304;
    const size_t mgE  = (size_t)DIM * DIM;
    const size_t m1E  = (size_t)DIM * MLPD;
    const size_t m2E  = (size_t)MLPD * DIM;
    unsigned short* qh  = wb;
    unsigned short* ql  = qh  + qkvE;
    unsigned short* mh  = ql  + qkvE;
    unsigned short* ml  = mh  + mgE;
    unsigned short* h1  = ml  + mgE;
    unsigned short* l1  = h1  + m1E;
    unsigned short* h2  = l1  + m1E;
    unsigned short* l2  = h2  + m2E;
    unsigned short* wmh = l2  + m2E;
    unsigned short* wml = wmh + mgE;

    patchify_kernel<<<(PROWS * DIM + 255) / 256, 256, 0, stream>>>(images, patches);
    class_pos_kernel<<<(NIMG * DIM + 255) / 256, 256, 0, stream>>>(ct, pos, x);
    convert_one<<<(DIM * (DIM / 32) + 255) / 256, 256, 0, stream>>>(W_map, wmh, wml, DIM, DIM);
    mgemm<1><<<dim3(DIM / 128, PROWS / 128), 256, 0, stream>>>(
        patches, wmh, wml, x, PROWS, DIM, DIM, nullptr, nullptr, pos, nullptr, nullptr, nullptr);

    const int mblk = (ROWS + 127) / 128;  // 50
    for (int l = 0; l < 12; ++l) {
        convert_layer<<<dim3(288, 4), 256, 0, stream>>>(
            qkv_w + (size_t)l * qkvE, merge_w + (size_t)l * mgE,
            mlp_w1 + (size_t)l * m1E, mlp_w2 + (size_t)l * m2E,
            qh, ql, mh, ml, h1, l1, h2, l2);
        ln_kernel<<<(ROWS + 3) / 4, 256, 0, stream>>>(x, ln1_w + l * DIM, ln1_b + l * DIM, h, ROWS);
        mgemm<2><<<dim3(2304 / 128, mblk), 256, 0, stream>>>(
            h, qh, ql, nullptr, ROWS, 2304, DIM, nullptr, nullptr, nullptr, qpl, kpl, vtp);
        attn_mfma<<<dim3(4, BHN), 256, 0, stream>>>(qpl, kpl, vtp, ob);
        mgemm<4><<<dim3(DIM / 128, mblk), 256, 0, stream>>>(
            ob, mh, ml, x, ROWS, DIM, DIM, nullptr, x, nullptr, nullptr, nullptr, nullptr);
        ln_kernel<<<(ROWS + 3) / 4, 256, 0, stream>>>(x, ln2_w + l * DIM, ln2_b + l * DIM, h, ROWS);
        mgemm<3><<<dim3(MLPD / 128, mblk), 256, 0, stream>>>(
            h, h1, l1, g, ROWS, MLPD, DIM, mlp_b1 + (size_t)l * MLPD, nullptr, nullptr, nullptr, nullptr, nullptr);
        mgemm<5><<<dim3(DIM / 128, mblk), 256, 0, stream>>>(
            g, h2, l2, x, ROWS, DIM, MLPD, mlp_b2 + (size_t)l * DIM, x, nullptr, nullptr, nullptr, nullptr);
    }
    head_kernel<<<NIMG, 256, 0, stream>>>(x, head_w, head_b, out);
}

// Round 4
// 5900.867 us; speedup vs baseline: 3.0535x; 1.0907x over previous
//
#include <hip/hip_runtime.h>
#include <math.h>

// ---------------- constants ----------------
#define NIMG 32
#define NP2  196        // patches per image
#define PTOK 197        // tokens per image
#define DIM  768
#define NH   12
#define VD   64
#define MLPD 3072
#define ROWS (NIMG*PTOK)   // 6304
#define PROWS (NIMG*NP2)   // 6272
#define MPAD 6400          // padded rows for activation planes (glds over-read)
#define PSTR 208           // padded token stride for q/k/v planes
#define BHN (NIMG*NH)      // 384

typedef float f32x4 __attribute__((ext_vector_type(4)));
typedef short bf16x8 __attribute__((ext_vector_type(8)));
typedef unsigned short u16x8 __attribute__((ext_vector_type(8)));
typedef unsigned short u16x4 __attribute__((ext_vector_type(4)));

__device__ __forceinline__ unsigned short f2bf(float x) {
    unsigned int u = __float_as_uint(x);
    return (unsigned short)((u + 0x7FFFu + ((u >> 16) & 1u)) >> 16);
}
__device__ __forceinline__ float bfhi(unsigned short h) {
    return __uint_as_float(((unsigned int)h) << 16);
}
// async global->LDS, 16B per lane; LDS dest = wave base + lane*16 (linear)
__device__ __forceinline__ void glds16(const unsigned short* g, unsigned short* l) {
    __builtin_amdgcn_global_load_lds(
        (const __attribute__((address_space(1))) unsigned int*)g,
        (__attribute__((address_space(3))) unsigned int*)l, 16, 0, 0);
}

// ---------------- patchify -> hi/lo bf16 planes ----------------
__global__ __launch_bounds__(256) void patchify_kernel(const float* __restrict__ img,
                                                       unsigned short* __restrict__ ph,
                                                       unsigned short* __restrict__ pl)
{
    int idx = blockIdx.x * 256 + threadIdx.x;
    if (idx >= PROWS * DIM) return;
    int row = idx / DIM, kk = idx % DIM;
    int b = row / NP2, p = row % NP2;
    int i = p / 14, j = p % 14;
    int c = kk >> 8, r = kk & 255;
    int pr = r >> 4, pw = r & 15;
    float v = img[(((size_t)b*3 + c)*224 + i*16 + pr)*224 + j*16 + pw];
    unsigned short hi = f2bf(v);
    ph[idx] = hi;
    pl[idx] = f2bf(v - bfhi(hi));
}

// ---------------- class token + pos row0 ----------------
__global__ __launch_bounds__(256) void class_pos_kernel(const float* __restrict__ ct,
                                                        const float* __restrict__ pos,
                                                        float* __restrict__ x)
{
    int idx = blockIdx.x * 256 + threadIdx.x;
    if (idx >= NIMG * DIM) return;
    int b = idx / DIM, d = idx % DIM;
    x[(size_t)b * PTOK * DIM + d] = ct[d] + pos[d];
}

// ---------------- weight conversion: W[K][N] fp32 -> blocked hi/lo bf16 ----------------
// Blocked: [N/128][K/32][128][32] row-major (n_in, k_in), 4096 elems / 8KB per block.
__device__ __forceinline__ void conv_body(const float* __restrict__ W,
    unsigned short* __restrict__ Bh, unsigned short* __restrict__ Bl, int K, int N)
{
    int idx = blockIdx.x * 256 + threadIdx.x;
    if (idx >= N * (K >> 5)) return;
    int kb = idx / N;
    int n  = idx - kb * N;
    size_t off = (((size_t)(n >> 7) * (K >> 5) + kb) * 128 + (n & 127)) * 32;
    #pragma unroll
    for (int u = 0; u < 4; ++u) {
        u16x8 h, l;
        #pragma unroll
        for (int j = 0; j < 8; ++j) {
            float x = W[(size_t)(kb * 32 + u * 8 + j) * N + n];
            unsigned short hh = f2bf(x);
            h[j] = hh;
            l[j] = f2bf(x - bfhi(hh));
        }
        *(u16x8*)&Bh[off + u * 8] = h;
        *(u16x8*)&Bl[off + u * 8] = l;
    }
}

__global__ __launch_bounds__(256) void convert_one(const float* __restrict__ W,
    unsigned short* __restrict__ Bh, unsigned short* __restrict__ Bl, int K, int N)
{
    conv_body(W, Bh, Bl, K, N);
}

__global__ __launch_bounds__(256) void convert_layer(
    const float* __restrict__ qw, const float* __restrict__ mw,
    const float* __restrict__ w1, const float* __restrict__ w2,
    unsigned short* qh, unsigned short* ql, unsigned short* mh, unsigned short* ml,
    unsigned short* h1, unsigned short* l1, unsigned short* h2, unsigned short* l2)
{
    switch (blockIdx.y) {
        case 0: conv_body(qw, qh, ql, DIM, 3*NH*VD); break;
        case 1: conv_body(mw, mh, ml, DIM, DIM);     break;
        case 2: conv_body(w1, h1, l1, DIM, MLPD);    break;
        case 3: conv_body(w2, h2, l2, MLPD, DIM);    break;
    }
}

// ---------------- split-bf16 MFMA GEMM, glds staging, 128x128 tile, BK=32 ----------------
// A: hi/lo bf16 planes, row-major [Mpad][K]. B: blocked hi/lo planes.
// grid = dim3(gm, gn)  (m fastest -> B-panel reuse per XCD, A L2-resident)
// LDS: linear 64B rows; 16B-slot XOR swizzle (slot ^ (row>>1)&3) baked into
// the GLOBAL source address (glds writes linearly) and applied on frag reads.
// MODE 1: embed(+pos)->x, 2: qkv->packed planes, 3: bias+gelu->hi/lo planes,
// 4: residual->x, 5: bias+residual->x
template<int MODE>
__global__ __launch_bounds__(256, 3) void mgemm(
    const unsigned short* __restrict__ Ah, const unsigned short* __restrict__ Al,
    const unsigned short* __restrict__ Bh, const unsigned short* __restrict__ Bl,
    float* __restrict__ C, int M, int N, int K,
    const float* __restrict__ bias, const float* __restrict__ res,
    const float* __restrict__ pos,
    unsigned int* __restrict__ qo, unsigned int* __restrict__ ko, unsigned int* __restrict__ vo,
    unsigned short* __restrict__ oph, unsigned short* __restrict__ opl)
{
    __shared__ unsigned short SAh[128 * 32];
    __shared__ unsigned short SAl[128 * 32];
    __shared__ unsigned short SBh[128 * 32];
    __shared__ unsigned short SBl[128 * 32];

    const int tid = threadIdx.x;
    const int m0 = blockIdx.x * 128, n0 = blockIdx.y * 128;
    const int wave = tid >> 6, lane = tid & 63;
    const int wm = (wave >> 1) * 64, wn = (wave & 1) * 64;
    const int lr = lane & 15, lg = lane >> 4;

    // staging source coords (slot pre-swizzled so linear LDS holds swizzled tile)
    const int r0 = tid >> 2, sl = tid & 3;
    const int s0 = sl ^ ((r0 >> 1) & 3);          // f(r0+64) == f(r0)
    const size_t aoff0 = (size_t)(m0 + r0) * K + s0 * 8;
    const size_t aoff1 = (size_t)(m0 + r0 + 64) * K + s0 * 8;
    const size_t boff0 = (size_t)(n0 >> 7) * (K >> 5) * 4096 + (size_t)r0 * 32 + s0 * 8;
    const size_t boff1 = boff0 + 64 * 32;
    unsigned short* dst0 = (unsigned short*)((char*)nullptr);
    (void)dst0;

    // frag read offsets (loop-invariant)
    int aro[4], bro[4];
    #pragma unroll
    for (int i = 0; i < 4; ++i) {
        int rowA = wm + i * 16 + lr;
        aro[i] = rowA * 32 + ((lg ^ ((rowA >> 1) & 3)) * 8);
        int rowB = wn + i * 16 + lr;
        bro[i] = rowB * 32 + ((lg ^ ((rowB >> 1) & 3)) * 8);
    }

    f32x4 acc[4][4];
    #pragma unroll
    for (int i = 0; i < 4; ++i)
        #pragma unroll
        for (int j = 0; j < 4; ++j)
            #pragma unroll
            for (int e = 0; e < 4; ++e) acc[i][j][e] = 0.f;

    const int kSteps = K >> 5;
    #pragma unroll 1
    for (int ks = 0; ks < kSteps; ++ks) {
        __syncthreads();                     // prev frag reads done
        const size_t ak = (size_t)ks * 32;
        const size_t bk = (size_t)ks * 4096;
        glds16(Ah + aoff0 + ak, SAh + tid * 8);
        glds16(Ah + aoff1 + ak, SAh + 2048 + tid * 8);
        glds16(Al + aoff0 + ak, SAl + tid * 8);
        glds16(Al + aoff1 + ak, SAl + 2048 + tid * 8);
        glds16(Bh + boff0 + bk, SBh + tid * 8);
        glds16(Bh + boff1 + bk, SBh + 2048 + tid * 8);
        glds16(Bl + boff0 + bk, SBl + tid * 8);
        glds16(Bl + boff1 + bk, SBl + 2048 + tid * 8);
        __syncthreads();                     // vmcnt(0) drained by compiler

        bf16x8 bfh[4], bfl[4];
        #pragma unroll
        for (int ni = 0; ni < 4; ++ni) {
            bfh[ni] = *(const bf16x8*)&SBh[bro[ni]];
            bfl[ni] = *(const bf16x8*)&SBl[bro[ni]];
        }
        #pragma unroll
        for (int mi = 0; mi < 4; ++mi) {
            bf16x8 afh = *(const bf16x8*)&SAh[aro[mi]];
            bf16x8 afl = *(const bf16x8*)&SAl[aro[mi]];
            #pragma unroll
            for (int ni = 0; ni < 4; ++ni) {
                acc[mi][ni] = __builtin_amdgcn_mfma_f32_16x16x32_bf16(afh, bfh[ni], acc[mi][ni], 0, 0, 0);
                acc[mi][ni] = __builtin_amdgcn_mfma_f32_16x16x32_bf16(afh, bfl[ni], acc[mi][ni], 0, 0, 0);
                acc[mi][ni] = __builtin_amdgcn_mfma_f32_16x16x32_bf16(afl, bfh[ni], acc[mi][ni], 0, 0, 0);
            }
        }
    }

    // epilogue: r = m0+wm+mi*16+lg*4+rr, c = n0+wn+ni*16+lr
    #pragma unroll
    for (int mi = 0; mi < 4; ++mi) {
        #pragma unroll
        for (int ni = 0; ni < 4; ++ni) {
            f32x4 v = acc[mi][ni];
            int c = n0 + wn + ni * 16 + lr;
            #pragma unroll
            for (int rr = 0; rr < 4; ++rr) {
                int r = m0 + wm + mi * 16 + lg * 4 + rr;
                if (r >= M) continue;
                float val = v[rr];
                if (MODE == 1) {
                    int b = r / NP2, p = r - b * NP2;
                    C[((size_t)b * PTOK + 1 + p) * DIM + c] = val + pos[(size_t)(p + 1) * DIM + c];
                } else if (MODE == 2) {
                    int b = r / PTOK, p = r - b * PTOK;
                    int t = c % 3, hv = c / 3;
                    int hd = hv >> 6, vv = hv & 63;
                    size_t bh = (size_t)b * NH + hd;
                    float sv = (t == 0) ? val * 0.125f : val;
                    unsigned short hi = f2bf(sv);
                    unsigned short lo = f2bf(sv - bfhi(hi));
                    unsigned int w32 = (unsigned int)hi | ((unsigned int)lo << 16);
                    if (t == 2) vo[(bh * 64 + vv) * PSTR + p] = w32;
                    else if (t == 0) qo[(bh * PSTR + p) * 64 + vv] = w32;
                    else ko[(bh * PSTR + p) * 64 + vv] = w32;
                } else if (MODE == 3) {
                    float tmp = val + bias[c];
                    float gel = 0.5f * tmp * (1.0f + erff(tmp * 0.70710678118654752f));
                    unsigned short hi = f2bf(gel);
                    oph[(size_t)r * N + c] = hi;
                    opl[(size_t)r * N + c] = f2bf(gel - bfhi(hi));
                } else if (MODE == 4) {
                    C[(size_t)r * N + c] = res[(size_t)r * N + c] + val;
                } else if (MODE == 5) {
                    C[(size_t)r * N + c] = res[(size_t)r * N + c] + val + bias[c];
                }
            }
        }
    }
}

// ---------------- LayerNorm -> hi/lo bf16 planes ----------------
__global__ __launch_bounds__(256) void ln_kernel(const float* __restrict__ x,
                                                 const float* __restrict__ w,
                                                 const float* __restrict__ b,
                                                 unsigned short* __restrict__ oh,
                                                 unsigned short* __restrict__ ol, int rows)
{
    int wave = threadIdx.x >> 6, lane = threadIdx.x & 63;
    int row = blockIdx.x * 4 + wave;
    if (row >= rows) return;
    const float* xr = x + (size_t)row * DIM;
    float vals[12];
    float sum = 0.f;
    #pragma unroll
    for (int u = 0; u < 12; ++u) { vals[u] = xr[u * 64 + lane]; sum += vals[u]; }
    #pragma unroll
    for (int off = 32; off; off >>= 1) sum += __shfl_xor(sum, off);
    float mean = sum * (1.f / DIM);
    float vs = 0.f;
    #pragma unroll
    for (int u = 0; u < 12; ++u) { float d = vals[u] - mean; vs += d * d; }
    #pragma unroll
    for (int off = 32; off; off >>= 1) vs += __shfl_xor(vs, off);
    float rstd = rsqrtf(vs * (1.f / DIM) + 1e-5f);
    #pragma unroll
    for (int u = 0; u < 12; ++u) {
        int d = u * 64 + lane;
        float v = (vals[u] - mean) * rstd * w[d] + b[d];
        unsigned short hi = f2bf(v);
        oh[(size_t)row * DIM + d] = hi;
        ol[(size_t)row * DIM + d] = f2bf(v - bfhi(hi));
    }
}

// ---------------- MFMA attention (round-3 structure, epilogue -> planes) ----------------
__global__ __launch_bounds__(256) void attn_mfma(
    const unsigned int* __restrict__ qp, const unsigned int* __restrict__ kp,
    const unsigned int* __restrict__ vtp,
    unsigned short* __restrict__ oh, unsigned short* __restrict__ ol)
{
    __shared__ unsigned short KVh[64 * 72];
    __shared__ unsigned short KVl[64 * 72];
    __shared__ unsigned short Ph[64 * 72];
    __shared__ unsigned short Pl[64 * 72];

    const int tid = threadIdx.x;
    const int w = tid >> 6, lane = tid & 63;
    const int l = lane & 15, g = lane >> 4;
    const int bh = blockIdx.y, q0 = blockIdx.x * 64;
    const int b = bh / NH, hd = bh - b * NH;

    int qrow = q0 + 16 * w + l;
    if (qrow >= PTOK) qrow = 0;
    const unsigned int* qbase = qp + ((size_t)bh * PSTR + qrow) * 64;
    bf16x8 qAh[2], qAl[2];
    #pragma unroll
    for (int ks = 0; ks < 2; ++ks) {
        const unsigned int* p = qbase + 32 * ks + 8 * g;
        uint4 a = *(const uint4*)p;
        uint4 c = *(const uint4*)(p + 4);
        bf16x8 h8, l8;
        h8[0]=(short)a.x; h8[1]=(short)a.y; h8[2]=(short)a.z; h8[3]=(short)a.w;
        h8[4]=(short)c.x; h8[5]=(short)c.y; h8[6]=(short)c.z; h8[7]=(short)c.w;
        l8[0]=(short)(a.x>>16); l8[1]=(short)(a.y>>16); l8[2]=(short)(a.z>>16); l8[3]=(short)(a.w>>16);
        l8[4]=(short)(c.x>>16); l8[5]=(short)(c.y>>16); l8[6]=(short)(c.z>>16); l8[7]=(short)(c.w>>16);
        qAh[ks] = h8; qAl[ks] = l8;
    }

    f32x4 s[13];
    #pragma unroll
    for (int t = 0; t < 13; ++t)
        #pragma unroll
        for (int e = 0; e < 4; ++e) s[t][e] = 0.f;

    for (int c = 0; c < 4; ++c) {
        __syncthreads();
        const int rows = (c < 3) ? 64 : 16;
        for (int u = tid; u < rows * 16; u += 256) {
            int r = u >> 4, cc = u & 15;
            int j = c * 64 + r;
            uint4 wv = make_uint4(0, 0, 0, 0);
            if (j < PTOK) wv = *(const uint4*)(kp + ((size_t)bh * PSTR + j) * 64 + cc * 4);
            u16x4 h4, l4;
            h4[0]=(unsigned short)wv.x; h4[1]=(unsigned short)wv.y;
            h4[2]=(unsigned short)wv.z; h4[3]=(unsigned short)wv.w;
            l4[0]=(unsigned short)(wv.x>>16); l4[1]=(unsigned short)(wv.y>>16);
            l4[2]=(unsigned short)(wv.z>>16); l4[3]=(unsigned short)(wv.w>>16);
            *(u16x4*)&KVh[r * 72 + cc * 4] = h4;
            *(u16x4*)&KVl[r * 72 + cc * 4] = l4;
        }
        __syncthreads();
        const int tc = (c < 3) ? 4 : 1;
        for (int t = 0; t < tc; ++t) {
            int ti = c * 4 + t;
            #pragma unroll
            for (int ks = 0; ks < 2; ++ks) {
                bf16x8 kh = *(const bf16x8*)&KVh[(16 * t + l) * 72 + 32 * ks + 8 * g];
                bf16x8 kl = *(const bf16x8*)&KVl[(16 * t + l) * 72 + 32 * ks + 8 * g];
                s[ti] = __builtin_amdgcn_mfma_f32_16x16x32_bf16(qAh[ks], kh, s[ti], 0, 0, 0);
                s[ti] = __builtin_amdgcn_mfma_f32_16x16x32_bf16(qAh[ks], kl, s[ti], 0, 0, 0);
                s[ti] = __builtin_amdgcn_mfma_f32_16x16x32_bf16(qAl[ks], kh, s[ti], 0, 0, 0);
            }
        }
    }

    if (l >= 5) {
        #pragma unroll
        for (int e = 0; e < 4; ++e) s[12][e] = -1e30f;
    }

    float mx[4], rs[4];
    #pragma unroll
    for (int e = 0; e < 4; ++e) {
        float m = s[0][e];
        #pragma unroll
        for (int t = 1; t < 13; ++t) m = fmaxf(m, s[t][e]);
        #pragma unroll
        for (int off = 1; off < 16; off <<= 1) m = fmaxf(m, __shfl_xor(m, off));
        mx[e] = m;
    }
    #pragma unroll
    for (int e = 0; e < 4; ++e) {
        float sum = 0.f;
        #pragma unroll
        for (int t = 0; t < 13; ++t) {
            float p = __expf(s[t][e] - mx[e]);
            s[t][e] = p;
            sum += p;
        }
        #pragma unroll
        for (int off = 1; off < 16; off <<= 1) sum += __shfl_xor(sum, off);
        rs[e] = 1.f / sum;
    }

    f32x4 o[4];
    #pragma unroll
    for (int t = 0; t < 4; ++t)
        #pragma unroll
        for (int e = 0; e < 4; ++e) o[t][e] = 0.f;

    for (int c = 0; c < 4; ++c) {
        __syncthreads();
        const int cols = (c < 3) ? 64 : 32;
        const int cpr = cols >> 2;
        for (int u = tid; u < 64 * cpr; u += 256) {
            int r = u / cpr, cc = u % cpr;
            int jbase = c * 64 + cc * 4;
            uint4 wv;
            if (c < 3) {
                wv = *(const uint4*)(vtp + ((size_t)bh * 64 + r) * PSTR + jbase);
            } else {
                unsigned int t0 = (jbase + 0 < PTOK) ? vtp[((size_t)bh * 64 + r) * PSTR + jbase + 0] : 0u;
                unsigned int t1 = (jbase + 1 < PTOK) ? vtp[((size_t)bh * 64 + r) * PSTR + jbase + 1] : 0u;
                unsigned int t2 = (jbase + 2 < PTOK) ? vtp[((size_t)bh * 64 + r) * PSTR + jbase + 2] : 0u;
                unsigned int t3 = (jbase + 3 < PTOK) ? vtp[((size_t)bh * 64 + r) * PSTR + jbase + 3] : 0u;
                wv = make_uint4(t0, t1, t2, t3);
            }
            u16x4 h4, l4;
            h4[0]=(unsigned short)wv.x; h4[1]=(unsigned short)wv.y;
            h4[2]=(unsigned short)wv.z; h4[3]=(unsigned short)wv.w;
            l4[0]=(unsigned short)(wv.x>>16); l4[1]=(unsigned short)(wv.y>>16);
            l4[2]=(unsigned short)(wv.z>>16); l4[3]=(unsigned short)(wv.w>>16);
            *(u16x4*)&KVh[r * 72 + cc * 4] = h4;
            *(u16x4*)&KVl[r * 72 + cc * 4] = l4;
        }
        const int tc = (c < 3) ? 4 : 1;
        for (int t = 0; t < tc; ++t) {
            int ti = c * 4 + t;
            #pragma unroll
            for (int e = 0; e < 4; ++e) {
                int row = 16 * w + 4 * g + e, col = 16 * t + l;
                float pv = s[ti][e];
                unsigned short hi = f2bf(pv);
                Ph[row * 72 + col] = hi;
                Pl[row * 72 + col] = f2bf(pv - bfhi(hi));
            }
        }
        __syncthreads();
        const int ksn = (c < 3) ? 2 : 1;
        for (int ks = 0; ks < ksn; ++ks) {
            bf16x8 pa_h = *(const bf16x8*)&Ph[(16 * w + l) * 72 + 32 * ks + 8 * g];
            bf16x8 pa_l = *(const bf16x8*)&Pl[(16 * w + l) * 72 + 32 * ks + 8 * g];
            #pragma unroll
            for (int tv = 0; tv < 4; ++tv) {
                bf16x8 vh = *(const bf16x8*)&KVh[(16 * tv + l) * 72 + 32 * ks + 8 * g];
                bf16x8 vl = *(const bf16x8*)&KVl[(16 * tv + l) * 72 + 32 * ks + 8 * g];
                o[tv] = __builtin_amdgcn_mfma_f32_16x16x32_bf16(pa_h, vh, o[tv], 0, 0, 0);
                o[tv] = __builtin_amdgcn_mfma_f32_16x16x32_bf16(pa_h, vl, o[tv], 0, 0, 0);
                o[tv] = __builtin_amdgcn_mfma_f32_16x16x32_bf16(pa_l, vh, o[tv], 0, 0, 0);
            }
        }
    }

    #pragma unroll
    for (int tv = 0; tv < 4; ++tv) {
        #pragma unroll
        for (int e = 0; e < 4; ++e) {
            int q = q0 + 16 * w + 4 * g + e;
            if (q < PTOK) {
                float v = o[tv][e] * rs[e];
                size_t idx = ((size_t)(b * PTOK + q)) * DIM + hd * 64 + 16 * tv + l;
                unsigned short hi = f2bf(v);
                oh[idx] = hi;
                ol[idx] = f2bf(v - bfhi(hi));
            }
        }
    }
}

// ---------------- head: logits + softmax ----------------
__global__ __launch_bounds__(256) void head_kernel(const float* __restrict__ x,
                                                   const float* __restrict__ W,
                                                   const float* __restrict__ bias,
                                                   float* __restrict__ out)
{
    __shared__ __align__(16) float xl[DIM];
    __shared__ float red[4];
    int b = blockIdx.x;
    const float* xr = x + (size_t)b * PTOK * DIM;
    for (int idx = threadIdx.x; idx < DIM; idx += 256) xl[idx] = xr[idx];
    __syncthreads();

    float logit[4];
    #pragma unroll
    for (int u = 0; u < 4; ++u) {
        int c = threadIdx.x + u * 256;
        float acc = (c < 1000) ? bias[c] : -INFINITY;
        if (c < 1000) {
            for (int k = 0; k < DIM; k += 4) {
                float4 xv = *(const float4*)&xl[k];
                acc += xv.x * W[(size_t)k * 1000 + c]
                     + xv.y * W[(size_t)(k + 1) * 1000 + c]
                     + xv.z * W[(size_t)(k + 2) * 1000 + c]
                     + xv.w * W[(size_t)(k + 3) * 1000 + c];
            }
        }
        logit[u] = acc;
    }
    int lane = threadIdx.x & 63, wv = threadIdx.x >> 6;
    float m = fmaxf(fmaxf(logit[0], logit[1]), fmaxf(logit[2], logit[3]));
    #pragma unroll
    for (int off = 32; off; off >>= 1) m = fmaxf(m, __shfl_xor(m, off));
    if (lane == 0) red[wv] = m;
    __syncthreads();
    m = fmaxf(fmaxf(red[0], red[1]), fmaxf(red[2], red[3]));

    float p[4]; float sum = 0.f;
    #pragma unroll
    for (int u = 0; u < 4; ++u) {
        int c = threadIdx.x + u * 256;
        p[u] = (c < 1000) ? expf(logit[u] - m) : 0.f;
        sum += p[u];
    }
    #pragma unroll
    for (int off = 32; off; off >>= 1) sum += __shfl_xor(sum, off);
    __syncthreads();
    if (lane == 0) red[wv] = sum;
    __syncthreads();
    float inv = 1.f / (red[0] + red[1] + red[2] + red[3]);
    #pragma unroll
    for (int u = 0; u < 4; ++u) {
        int c = threadIdx.x + u * 256;
        if (c < 1000) out[(size_t)b * 1000 + c] = p[u] * inv;
    }
}

// ---------------- launcher ----------------
extern "C" void kernel_launch(void* const* d_in, const int* in_sizes, int n_in,
                              void* d_out, int out_size, void* d_ws, size_t ws_size,
                              hipStream_t stream)
{
    const float* images  = (const float*)d_in[0];
    const float* W_map   = (const float*)d_in[1];
    const float* ct      = (const float*)d_in[2];
    const float* pos     = (const float*)d_in[3];
    const float* ln1_w   = (const float*)d_in[4];
    const float* ln1_b   = (const float*)d_in[5];
    const float* qkv_w   = (const float*)d_in[6];
    const float* merge_w = (const float*)d_in[7];
    const float* ln2_w   = (const float*)d_in[8];
    const float* ln2_b   = (const float*)d_in[9];
    const float* mlp_w1  = (const float*)d_in[10];
    const float* mlp_b1  = (const float*)d_in[11];
    const float* mlp_w2  = (const float*)d_in[12];
    const float* mlp_b2  = (const float*)d_in[13];
    const float* head_w  = (const float*)d_in[14];
    const float* head_b  = (const float*)d_in[15];
    float* out = (float*)d_out;

    float* ws = (float*)d_ws;
    const size_t XE   = (size_t)ROWS * DIM;
    const size_t PLND = (size_t)MPAD * DIM;    // activation plane (DIM wide)
    const size_t GPL  = (size_t)MPAD * MLPD;   // gelu plane (MLPD wide)

    float* x = ws;
    unsigned short* hh = (unsigned short*)(x + XE);
    unsigned short* hl = hh + PLND;
    unsigned short* oh = hl + PLND;
    unsigned short* ol = oh + PLND;
    unsigned short* gh = ol + PLND;
    unsigned short* gl = gh + GPL;

    // aliases on g region (lifetimes disjoint)
    const size_t PL = (size_t)BHN * PSTR * 64;         // 5,111,808 u32
    unsigned int* qpl = (unsigned int*)gh;             // q/k/v live qkv->attn
    unsigned int* kpl = qpl + PL;
    unsigned int* vtp = kpl + PL;
    unsigned short* pph = gh;                          // patches live pre-loop
    unsigned short* ppl = pph + (size_t)PROWS * DIM;

    // weight hi/lo planes after gl
    unsigned short* wb = gl + GPL;
    const size_t qkvE = (size_t)DIM * 2304;
    const size_t mgE  = (size_t)DIM * DIM;
    const size_t m1E  = (size_t)DIM * MLPD;
    const size_t m2E  = (size_t)MLPD * DIM;
    unsigned short* qh  = wb;
    unsigned short* ql  = qh  + qkvE;
    unsigned short* mh  = ql  + qkvE;
    unsigned short* ml  = mh  + mgE;
    unsigned short* h1  = ml  + mgE;
    unsigned short* l1  = h1  + m1E;
    unsigned short* h2  = l1  + m1E;
    unsigned short* l2  = h2  + m2E;
    unsigned short* wmh = l2  + m2E;
    unsigned short* wml = wmh + mgE;

    patchify_kernel<<<(PROWS * DIM + 255) / 256, 256, 0, stream>>>(images, pph, ppl);
    class_pos_kernel<<<(NIMG * DIM + 255) / 256, 256, 0, stream>>>(ct, pos, x);
    convert_one<<<(DIM * (DIM / 32) + 255) / 256, 256, 0, stream>>>(W_map, wmh, wml, DIM, DIM);
    mgemm<1><<<dim3(PROWS / 128, DIM / 128), 256, 0, stream>>>(
        pph, ppl, wmh, wml, x, PROWS, DIM, DIM,
        nullptr, nullptr, pos, nullptr, nullptr, nullptr, nullptr, nullptr);

    const int gm = (ROWS + 127) / 128;  // 50
    for (int l = 0; l < 12; ++l) {
        convert_layer<<<dim3(288, 4), 256, 0, stream>>>(
            qkv_w + (size_t)l * qkvE, merge_w + (size_t)l * mgE,
            mlp_w1 + (size_t)l * m1E, mlp_w2 + (size_t)l * m2E,
            qh, ql, mh, ml, h1, l1, h2, l2);
        ln_kernel<<<(ROWS + 3) / 4, 256, 0, stream>>>(x, ln1_w + l * DIM, ln1_b + l * DIM, hh, hl, ROWS);
        mgemm<2><<<dim3(gm, 2304 / 128), 256, 0, stream>>>(
            hh, hl, qh, ql, nullptr, ROWS, 2304, DIM,
            nullptr, nullptr, nullptr, qpl, kpl, vtp, nullptr, nullptr);
        attn_mfma<<<dim3(4, BHN), 256, 0, stream>>>(qpl, kpl, vtp, oh, ol);
        mgemm<4><<<dim3(gm, DIM / 128), 256, 0, stream>>>(
            oh, ol, mh, ml, x, ROWS, DIM, DIM,
            nullptr, x, nullptr, nullptr, nullptr, nullptr, nullptr, nullptr);
        ln_kernel<<<(ROWS + 3) / 4, 256, 0, stream>>>(x, ln2_w + l * DIM, ln2_b + l * DIM, hh, hl, ROWS);
        mgemm<3><<<dim3(gm, MLPD / 128), 256, 0, stream>>>(
            hh, hl, h1, l1, nullptr, ROWS, MLPD, DIM,
            mlp_b1 + (size_t)l * MLPD, nullptr, nullptr, nullptr, nullptr, nullptr, gh, gl);
        mgemm<5><<<dim3(gm, DIM / 128), 256, 0, stream>>>(
            gh, gl, h2, l2, x, ROWS, DIM, MLPD,
            mlp_b2 + (size_t)l * DIM, x, nullptr, nullptr, nullptr, nullptr, nullptr, nullptr);
    }
    head_kernel<<<NIMG, 256, 0, stream>>>(x, head_w, head_b, out);
}